// Round 10
// baseline (172.164 us; speedup 1.0000x reference)
//
#include <hip/hip_runtime.h>
#include <math.h>

#define HW    16384
#define NTOK  32768
#define CDIM  128
#define HFDIM 512
#define NEXP  6

typedef __attribute__((ext_vector_type(8))) short short8;
typedef __attribute__((ext_vector_type(8))) unsigned short ushort8v;
typedef __attribute__((ext_vector_type(16))) float f32x16;
typedef unsigned long long u64;

// workspace byte offsets (256-aligned)
#define OFF_XFB    0UL          // N*128 bf16      = 8,388,608
#define OFF_LIST   8388608UL    // E*N int         =   786,432
#define OFF_GATES  9175040UL    // 2N float        =   262,144
#define OFF_OUTBUF 9437184UL    // 2N*128 bf16     = 16,777,216
#define OFF_WT1    42991616UL   // E*512*128 bf16  =   786,432  [e][hf][C]
#define OFF_WT2    43778048UL   // E*128*512 bf16  =   786,432  [e][c][hf]
#define OFF_BIAS   44564480UL
#define OFF_CNT    44564736UL
#define OFF_WSUM   44564992UL

__device__ __forceinline__ unsigned int bf16_1(float f) {
    unsigned int u = __float_as_uint(f);
    return (u + 0x7FFFu + ((u >> 16) & 1)) >> 16;
}
__device__ __forceinline__ unsigned int bf16pair(float lo, float hi) {
    return bf16_1(lo) | (bf16_1(hi) << 16);
}
// sigmoid-form gelu: x*sigmoid(1.702x); ~5 VALU inst
__device__ __forceinline__ float gelu_f(float v) {
    return __fdividef(v, 1.0f + __expf(-1.702f * v));
}
__device__ __forceinline__ short8 mk8(unsigned a, unsigned b, unsigned c, unsigned d) {
    union { unsigned u[4]; short8 s; } x;
    x.u[0] = a; x.u[1] = b; x.u[2] = c; x.u[3] = d;
    return x.s;
}

__device__ __forceinline__ f32x16 MFMA_B(short8 a, short8 b, f32x16 c) {
    return __builtin_amdgcn_mfma_f32_32x32x16_bf16(a, b, c, 0, 0, 0);
}

// K0: per-batch gating bias + zero atomics (deterministic per call)
__global__ __launch_bounds__(64) void prep_kernel(
    const float* __restrict__ prompt, const float* __restrict__ de_cls,
    const float* __restrict__ w_g, const float* __restrict__ gate_boost,
    const float* __restrict__ degra_w, const float* __restrict__ degra_b,
    float* __restrict__ bias, int* __restrict__ cnt, float* __restrict__ wsum)
{
    int t = threadIdx.x;
    if (t < 2 * NEXP) {
        int b = t / NEXP, e = t % NEXP;
        float acc = 0.f;
        for (int c = 0; c < CDIM; ++c)
            acc = fmaf(prompt[b*CDIM + c], w_g[(CDIM + c)*NEXP + e], acc);
        float db = 0.f;
        for (int d = 0; d < 6; ++d)
            db = fmaf(de_cls[b*6 + d], degra_w[d*NEXP + e], db);
        bias[b*NEXP + e] = acc + gate_boost[0] * (db + degra_b[e]);
    }
    if (t >= 32 && t < 32 + NEXP) cnt[t - 32] = 0;
    if (t >= 40 && t < 40 + NEXP) wsum[t - 40] = 0.f;
}

// Kw: fp32 weights -> bf16, plain transposed layouts (weights go straight to
// registers in the expert kernel; no LDS, no swizzle).
// wt1: [e][hf 512][k=C 128]   rows 256B
// wt2: [e][c 128][k=hf 512]   rows 1KB
__global__ __launch_bounds__(256) void wconv_kernel(
    const float* __restrict__ fc1_w, const float* __restrict__ fc2_w,
    unsigned short* __restrict__ wt1, unsigned short* __restrict__ wt2)
{
    __shared__ unsigned short ls[128][128];   // [k][col] bf16, 32 KB
    const int bid = blockIdx.x;               // e*8 + which*4 + chunk
    const int e = bid >> 3, which = (bid >> 2) & 1, ch = bid & 3;
    const int t = threadIdx.x;
    #pragma unroll 4
    for (int i = 0; i < 16; ++i) {
        int id = t + 256 * i;                 // 4096 float4 tasks
        int k = id >> 5, q = id & 31;
        const float* p = which
            ? (fc2_w + (size_t)e*65536 + (size_t)(ch*128 + k)*128 + q*4)
            : (fc1_w + (size_t)e*65536 + (size_t)k*512 + ch*128 + q*4);
        float4 v = *(const float4*)p;
        u64 pk = (u64)bf16_1(v.x) | ((u64)bf16_1(v.y) << 16)
               | ((u64)bf16_1(v.z) << 32) | ((u64)bf16_1(v.w) << 48);
        *(u64*)&ls[k][q*4] = pk;
    }
    __syncthreads();
    #pragma unroll 2
    for (int i = 0; i < 8; ++i) {
        int id = t + 256 * i;                 // 2048 tasks: (col, kg)
        int col = id & 127, kg = id >> 7;     // kg = k-group of 8 (0..15)
        unsigned short v[8];
        #pragma unroll
        for (int j = 0; j < 8; ++j) v[j] = ls[kg*8 + j][col];
        int4 pk;
        pk.x = v[0] | (v[1] << 16); pk.y = v[2] | (v[3] << 16);
        pk.z = v[4] | (v[5] << 16); pk.w = v[6] | (v[7] << 16);
        if (which) {
            *(int4*)(wt2 + (size_t)e*65536 + (size_t)col*512 + ch*128 + kg*8) = pk;
        } else {
            *(int4*)(wt1 + (((size_t)(e*4 + ch)) << 14) + (size_t)col*128 + kg*8) = pk;
        }
    }
}

// K1: transpose x -> xfb (token-major bf16), gating, top-2 softmax, lists.
__global__ __launch_bounds__(256) void gate_kernel(
    const float* __restrict__ x, const float* __restrict__ w_g,
    const float* __restrict__ bias, unsigned short* __restrict__ xfb,
    int* __restrict__ list, float* __restrict__ gates,
    int* __restrict__ cnt, float* __restrict__ wsum)
{
    __shared__ float xs[CDIM][65];
    __shared__ float wgs[CDIM][NEXP];
    __shared__ int   cnt_s[NEXP];
    __shared__ float ws_s[NEXP];
    __shared__ int   base_s[NEXP];
    const int t = threadIdx.x;
    const int n0 = blockIdx.x * 64;
    const int b = n0 >> 14;
    const int hw0 = n0 & (HW - 1);

    for (int i = t; i < CDIM * NEXP; i += 256) wgs[i / NEXP][i % NEXP] = w_g[i];
    if (t < NEXP) { cnt_s[t] = 0; ws_s[t] = 0.f; }

    const float* xb = x + (size_t)b * CDIM * HW + hw0;
    #pragma unroll 4
    for (int i = 0; i < 32; ++i) {
        int idx = t + 256 * i;
        int c = idx >> 6, j = idx & 63;
        xs[c][j] = xb[(size_t)c * HW + j];
    }
    __syncthreads();
    unsigned int* xo = (unsigned int*)xfb;
    #pragma unroll 4
    for (int i = 0; i < 16; ++i) {
        int idx = t + 256 * i;
        int tk = idx >> 6, cp = idx & 63;
        xo[(size_t)(n0 + tk) * 64 + cp] = bf16pair(xs[2*cp][tk], xs[2*cp+1][tk]);
    }

    int i0 = 0, i1 = 0, s0 = 0, s1 = 0;
    float g0 = 0.f, g1 = 0.f;
    if (t < 64) {
        float lg[NEXP];
        #pragma unroll
        for (int e = 0; e < NEXP; ++e) lg[e] = bias[b*NEXP + e];
        for (int c = 0; c < CDIM; ++c) {
            float xv = xs[c][t];
            #pragma unroll
            for (int e = 0; e < NEXP; ++e) lg[e] = fmaf(xv, wgs[c][e], lg[e]);
        }
        i0 = 0;
        #pragma unroll
        for (int e = 1; e < NEXP; ++e) if (lg[e] > lg[i0]) i0 = e;
        i1 = (i0 == 0) ? 1 : 0;
        #pragma unroll
        for (int e = 0; e < NEXP; ++e) if (e != i0 && lg[e] > lg[i1]) i1 = e;
        float e1 = expf(lg[i1] - lg[i0]);
        g0 = 1.f / (1.f + e1);
        g1 = e1 * g0;
        s0 = atomicAdd(&cnt_s[i0], 1);
        s1 = atomicAdd(&cnt_s[i1], 1);
        atomicAdd(&ws_s[i0], g0);
        atomicAdd(&ws_s[i1], g1);
    }
    __syncthreads();
    if (t < NEXP) {
        base_s[t] = atomicAdd(&cnt[t], cnt_s[t]);
        atomicAdd(&wsum[t], ws_s[t]);
    }
    __syncthreads();
    if (t < 64) {
        int n = n0 + t;
        list[i0 * NTOK + base_s[i0] + s0] = 2 * n;
        list[i1 * NTOK + base_s[i1] + s1] = 2 * n + 1;
        gates[2 * n]     = g0;
        gates[2 * n + 1] = g1;
    }
}

// K2: balance loss
__global__ void loss_kernel(const int* __restrict__ cnt,
                            const float* __restrict__ wsum,
                            float* __restrict__ out_loss)
{
    if (threadIdx.x == 0 && blockIdx.x == 0) {
        float mw = 0.f, mc = 0.f;
        for (int e = 0; e < NEXP; ++e) { mw += wsum[e]; mc += (float)cnt[e]; }
        mw /= NEXP; mc /= NEXP;
        float vw = 0.f, vc = 0.f;
        for (int e = 0; e < NEXP; ++e) {
            float dw = wsum[e] - mw, dc = (float)cnt[e] - mc;
            vw += dw * dw; vc += dc * dc;
        }
        vw /= (NEXP - 1); vc /= (NEXP - 1);
        out_loss[0] = vw / (mw * mw + 1e-10f) + vc / (mc * mc + 1e-10f);
    }
}

// K3: barrier-free, LDS-free MFMA expert MLP -- parallelism-first.
// 1 wave per block, 32 tokens per wave -> ~2048 working waves (2/SIMD, the
// r6-vs-r9 evidence says resident-wave count is THE lever in this regime).
// Weights stream global->regs, software-pipelined: each load batch is issued
// a full compute phase before its use (W2 covered by gelu/pack, W1next
// covered by gelu+GEMM2+loop). hid stays in registers (r7-verified exchange).
__global__ __launch_bounds__(64, 2) void expert_kernel(
    const unsigned short* __restrict__ xfb, const int* __restrict__ list,
    const int* __restrict__ cnt, const float* __restrict__ gates,
    const unsigned short* __restrict__ wt1, const unsigned short* __restrict__ wt2,
    const float* __restrict__ fc1_b, const float* __restrict__ fc2_b,
    unsigned short* __restrict__ outbuf)
{
    const int e = blockIdx.x;
    const int ne = cnt[e];
    const int base = blockIdx.y * 32;
    if (base >= ne) return;
    const int l = threadIdx.x;
    const int l31 = l & 31, lh = l >> 5;
    const bool islo = (l < 32);

    int r = base + l31;
    int a = (r < ne) ? list[e*NTOK + r] : -1;
    float g = (a >= 0) ? gates[a] : 0.f;
    int tok = (a >= 0) ? (a >> 1) : 0;

    // X B-fragments: lane holds X[k = ks*16 + lh*8 ..+7][tok = l31]
    short8 afr[8];
    {
        const unsigned short* xr = xfb + (size_t)tok*128 + lh*8;
        #pragma unroll
        for (int ks = 0; ks < 8; ++ks)
            afr[ks] = *(const short8*)(xr + ks*16);
    }

    f32x16 zz;
    #pragma unroll
    for (int i = 0; i < 16; ++i) zz[i] = 0.0f;
    f32x16 o0 = zz, o1 = zz, o2 = zz, o3 = zz;

    const unsigned short* w1e = wt1 + ((size_t)e << 16);
    const unsigned short* w2e = wt2 + ((size_t)e << 16);

    // preload W1(gp=0): row = l31 (hf), k = ks*16 + lh*8
    short8 wf[8];
    {
        const unsigned short* wr = w1e + (size_t)l31*128 + lh*8;
        #pragma unroll
        for (int ks = 0; ks < 8; ++ks)
            wf[ks] = *(const short8*)(wr + ks*16);
    }

    for (int gp = 0; gp < 16; ++gp) {         // 32-hf chunks
        // GEMM1: C1[hf 32][tok 32], k = C = 128 (consumes wf at issue)
        f32x16 c1 = zz;
        #pragma unroll
        for (int ks = 0; ks < 8; ++ks)
            c1 = MFMA_B(wf[ks], afr[ks], c1);

        // issue W2(gp) loads -- covered by gelu/pack below
        short8 w2r[8];
        {
            const unsigned short* c0 = w2e + (size_t)l31*512        + gp*32 + lh*8;
            const unsigned short* c1p = w2e + (size_t)(32 + l31)*512 + gp*32 + lh*8;
            const unsigned short* c2 = w2e + (size_t)(64 + l31)*512 + gp*32 + lh*8;
            const unsigned short* c3 = w2e + (size_t)(96 + l31)*512 + gp*32 + lh*8;
            w2r[0] = *(const short8*)(c0);  w2r[1] = *(const short8*)(c0 + 16);
            w2r[2] = *(const short8*)(c1p); w2r[3] = *(const short8*)(c1p + 16);
            w2r[4] = *(const short8*)(c2);  w2r[5] = *(const short8*)(c2 + 16);
            w2r[6] = *(const short8*)(c3);  w2r[7] = *(const short8*)(c3 + 16);
        }
        // issue W1(gp+1) loads -- covered by gelu + GEMM2 + loop-back
        if (gp < 15) {
            const unsigned short* wr = w1e + (size_t)((gp + 1)*32 + l31)*128 + lh*8;
            #pragma unroll
            for (int ks = 0; ks < 8; ++ks)
                wf[ks] = *(const short8*)(wr + ks*16);
        }

        // bias + gelu + pack + cross-half exchange -> pa frags (r7-verified)
        const float* bb = fc1_b + (size_t)e*HFDIM + gp*32 + 4*lh;
        float4 b0 = *(const float4*)(bb);
        float4 b1 = *(const float4*)(bb + 8);
        float4 b2 = *(const float4*)(bb + 16);
        float4 b3 = *(const float4*)(bb + 24);
        float bias[16] = {b0.x, b0.y, b0.z, b0.w, b1.x, b1.y, b1.z, b1.w,
                          b2.x, b2.y, b2.z, b2.w, b3.x, b3.y, b3.z, b3.w};
        unsigned int pr[8];
        #pragma unroll
        for (int i = 0; i < 8; ++i) {
            pr[i] = bf16pair(gelu_f(c1[2*i]   + bias[2*i]),
                             gelu_f(c1[2*i+1] + bias[2*i+1]));
        }
        unsigned int rx0 = __shfl_xor(islo ? pr[2] : pr[0], 32);
        unsigned int rx1 = __shfl_xor(islo ? pr[3] : pr[1], 32);
        unsigned int rx2 = __shfl_xor(islo ? pr[6] : pr[4], 32);
        unsigned int rx3 = __shfl_xor(islo ? pr[7] : pr[5], 32);
        short8 pa0 = mk8(islo ? pr[0] : rx0, islo ? pr[1] : rx1,
                         islo ? rx0 : pr[2], islo ? rx1 : pr[3]);
        short8 pa1 = mk8(islo ? pr[4] : rx2, islo ? pr[5] : rx3,
                         islo ? rx2 : pr[6], islo ? rx3 : pr[7]);

        // GEMM2 partial: k = gp*32 + lh*8 (+16)
        o0 = MFMA_B(pa0, w2r[0], o0); o0 = MFMA_B(pa1, w2r[1], o0);
        o1 = MFMA_B(pa0, w2r[2], o1); o1 = MFMA_B(pa1, w2r[3], o1);
        o2 = MFMA_B(pa0, w2r[4], o2); o2 = MFMA_B(pa1, w2r[5], o2);
        o3 = MFMA_B(pa0, w2r[6], o3); o3 = MFMA_B(pa1, w2r[7], o3);
    }

    // epilogue: gate * exp(out + fc2_b) -> bf16 scatter to outbuf[a]
    float bc0 = fc2_b[(size_t)e*CDIM + l31];
    float bc1 = fc2_b[(size_t)e*CDIM + 32 + l31];
    float bc2 = fc2_b[(size_t)e*CDIM + 64 + l31];
    float bc3 = fc2_b[(size_t)e*CDIM + 96 + l31];
    #pragma unroll
    for (int rr = 0; rr < 16; ++rr) {
        int crow = (rr & 3) + 8*(rr >> 2) + 4*lh;
        int av   = __shfl(a, crow);
        float gv = __shfl(g, crow);
        if (av < 0) continue;
        unsigned short* po = outbuf + (size_t)av*CDIM + l31;
        po[0]  = (unsigned short)bf16_1(gv * __expf(o0[rr] + bc0));
        po[32] = (unsigned short)bf16_1(gv * __expf(o1[rr] + bc1));
        po[64] = (unsigned short)bf16_1(gv * __expf(o2[rr] + bc2));
        po[96] = (unsigned short)bf16_1(gv * __expf(o3[rr] + bc3));
    }
}

// K4: y = log(p0 + p1) from bf16 partials, transpose back to (B,C,H,W)
__global__ __launch_bounds__(256) void combine_kernel(
    const unsigned short* __restrict__ outbuf, float* __restrict__ out)
{
    __shared__ float ys[64][129];
    const int t = threadIdx.x;
    const int n0 = blockIdx.x * 64;
    const int b = n0 >> 14;
    const int hw0 = n0 & (HW - 1);
    #pragma unroll
    for (int i = 0; i < 4; ++i) {
        int idx = t + 256 * i;            // 1024 tasks: token x 16-col group
        int tk = idx >> 4, c8 = (idx & 15) * 8;
        const unsigned short* p = outbuf + (size_t)(n0 + tk) * 256 + c8;
        ushort8v p0 = *(const ushort8v*)p;
        ushort8v p1 = *(const ushort8v*)(p + 128);
        const float EPSL = 2.2204460492503131e-16f;
        #pragma unroll
        for (int j = 0; j < 8; ++j) {
            float v = __uint_as_float((unsigned)p0[j] << 16)
                    + __uint_as_float((unsigned)p1[j] << 16);
            ys[tk][c8 + j] = __logf(v == 0.f ? EPSL : v);
        }
    }
    __syncthreads();
    float* ob = out + (size_t)b * CDIM * HW + hw0;
    #pragma unroll 4
    for (int i = 0; i < 32; ++i) {
        int idx = t + 256 * i;
        int c = idx >> 6;
        int j = idx & 63;
        ob[(size_t)c * HW + j] = ys[j][c];
    }
}

extern "C" void kernel_launch(void* const* d_in, const int* in_sizes, int n_in,
                              void* d_out, int out_size, void* d_ws, size_t ws_size,
                              hipStream_t stream)
{
    const float* x       = (const float*)d_in[0];
    const float* prompt  = (const float*)d_in[1];
    const float* de_cls  = (const float*)d_in[2];
    const float* w_g     = (const float*)d_in[3];
    const float* gboost  = (const float*)d_in[4];
    const float* degra_w = (const float*)d_in[5];
    const float* degra_b = (const float*)d_in[6];
    const float* fc1_w   = (const float*)d_in[7];
    const float* fc1_b   = (const float*)d_in[8];
    const float* fc2_w   = (const float*)d_in[9];
    const float* fc2_b   = (const float*)d_in[10];
    float* out = (float*)d_out;
    char* ws = (char*)d_ws;

    unsigned short* xfb  = (unsigned short*)(ws + OFF_XFB);
    int*   list   = (int*)(ws + OFF_LIST);
    float* gates  = (float*)(ws + OFF_GATES);
    unsigned short* outbuf = (unsigned short*)(ws + OFF_OUTBUF);
    unsigned short* wt1 = (unsigned short*)(ws + OFF_WT1);
    unsigned short* wt2 = (unsigned short*)(ws + OFF_WT2);
    float* bias   = (float*)(ws + OFF_BIAS);
    int*   cnt    = (int*)(ws + OFF_CNT);
    float* wsum   = (float*)(ws + OFF_WSUM);

    prep_kernel<<<1, 64, 0, stream>>>(prompt, de_cls, w_g, gboost, degra_w,
                                      degra_b, bias, cnt, wsum);
    wconv_kernel<<<48, 256, 0, stream>>>(fc1_w, fc2_w, wt1, wt2);
    gate_kernel<<<512, 256, 0, stream>>>(x, w_g, bias, xfb, list, gates, cnt, wsum);
    loss_kernel<<<1, 64, 0, stream>>>(cnt, wsum, out + (size_t)NTOK * CDIM);
    dim3 eg(NEXP, 1024);  // 32-token tiles per 1-wave block (~2048 working)
    expert_kernel<<<eg, 64, 0, stream>>>(xfb, list, cnt, gates, wt1, wt2,
                                         fc1_b, fc2_b, outbuf);
    combine_kernel<<<512, 256, 0, stream>>>(outbuf, out);
}

// Round 11
// 136.662 us; speedup vs baseline: 1.2598x; 1.2598x over previous
//
#include <hip/hip_runtime.h>
#include <math.h>

#define HW    16384
#define NTOK  32768
#define CDIM  128
#define HFDIM 512
#define NEXP  6

typedef __attribute__((ext_vector_type(8))) short short8;
typedef __attribute__((ext_vector_type(8))) unsigned short ushort8v;
typedef __attribute__((ext_vector_type(16))) float f32x16;
typedef unsigned long long u64;

// workspace byte offsets (256-aligned)
#define OFF_XFB    0UL          // N*128 bf16      = 8,388,608
#define OFF_LIST   8388608UL    // E*N int         =   786,432
#define OFF_GATES  9175040UL    // 2N float        =   262,144
#define OFF_OUTBUF 9437184UL    // 2N*128 bf16     = 16,777,216
#define OFF_WT1    42991616UL   // E*16*8*64 frag bf16 = 786,432  (fragment-order)
#define OFF_WT2    43778048UL   // E*16*8*64 frag bf16 = 786,432  (fragment-order)
#define OFF_BIAS   44564480UL
#define OFF_CNT    44564736UL
#define OFF_WSUM   44564992UL

__device__ __forceinline__ unsigned int bf16_1(float f) {
    unsigned int u = __float_as_uint(f);
    return (u + 0x7FFFu + ((u >> 16) & 1)) >> 16;
}
__device__ __forceinline__ unsigned int bf16pair(float lo, float hi) {
    return bf16_1(lo) | (bf16_1(hi) << 16);
}
// sigmoid-form gelu: x*sigmoid(1.702x); ~5 VALU inst
__device__ __forceinline__ float gelu_f(float v) {
    return __fdividef(v, 1.0f + __expf(-1.702f * v));
}
__device__ __forceinline__ short8 mk8(unsigned a, unsigned b, unsigned c, unsigned d) {
    union { unsigned u[4]; short8 s; } x;
    x.u[0] = a; x.u[1] = b; x.u[2] = c; x.u[3] = d;
    return x.s;
}

__device__ __forceinline__ f32x16 MFMA_B(short8 a, short8 b, f32x16 c) {
    return __builtin_amdgcn_mfma_f32_32x32x16_bf16(a, b, c, 0, 0, 0);
}

// K0: per-batch gating bias + zero atomics (deterministic per call)
__global__ __launch_bounds__(64) void prep_kernel(
    const float* __restrict__ prompt, const float* __restrict__ de_cls,
    const float* __restrict__ w_g, const float* __restrict__ gate_boost,
    const float* __restrict__ degra_w, const float* __restrict__ degra_b,
    float* __restrict__ bias, int* __restrict__ cnt, float* __restrict__ wsum)
{
    int t = threadIdx.x;
    if (t < 2 * NEXP) {
        int b = t / NEXP, e = t % NEXP;
        float acc = 0.f;
        for (int c = 0; c < CDIM; ++c)
            acc = fmaf(prompt[b*CDIM + c], w_g[(CDIM + c)*NEXP + e], acc);
        float db = 0.f;
        for (int d = 0; d < 6; ++d)
            db = fmaf(de_cls[b*6 + d], degra_w[d*NEXP + e], db);
        bias[b*NEXP + e] = acc + gate_boost[0] * (db + degra_b[e]);
    }
    if (t >= 32 && t < 32 + NEXP) cnt[t - 32] = 0;
    if (t >= 40 && t < 40 + NEXP) wsum[t - 40] = 0.f;
}

// Kw: fp32 weights -> bf16 in MFMA-FRAGMENT ORDER so the expert kernel's
// weight loads are fully coalesced (lane l reads base + l*16).
// wt1: [e][gp 16][ks 8][lane 64][8 bf16]; lane l = (hf&31) + 32*lh holds
//      W1T[hf = gp*32 + (l&31)][C = ks*16 + (l>>5)*8 ..+7]
// wt2: [e][gp 16][i=2*ct+s 8][lane 64][8 bf16]; lane l holds
//      W2T[c = ct*32 + (l&31)][hf = gp*32 + (l>>5)*8 + s*16 ..+7]
__global__ __launch_bounds__(256) void wconv_kernel(
    const float* __restrict__ fc1_w, const float* __restrict__ fc2_w,
    unsigned short* __restrict__ wt1, unsigned short* __restrict__ wt2)
{
    __shared__ unsigned short ls[128][128];   // [k][col] bf16, 32 KB
    const int bid = blockIdx.x;               // e*8 + which*4 + chunk
    const int e = bid >> 3, which = (bid >> 2) & 1, ch = bid & 3;
    const int t = threadIdx.x;
    #pragma unroll 4
    for (int i = 0; i < 16; ++i) {
        int id = t + 256 * i;                 // 4096 float4 tasks
        int k = id >> 5, q = id & 31;
        // which=0: ls[k=C][col=hf_local]  from fc1_w[e][k][ch*128+col]
        // which=1: ls[k=hf_local][col=c]  from fc2_w[e][ch*128+k][col]
        const float* p = which
            ? (fc2_w + (size_t)e*65536 + (size_t)(ch*128 + k)*128 + q*4)
            : (fc1_w + (size_t)e*65536 + (size_t)k*512 + ch*128 + q*4);
        float4 v = *(const float4*)p;
        u64 pk = (u64)bf16_1(v.x) | ((u64)bf16_1(v.y) << 16)
               | ((u64)bf16_1(v.z) << 32) | ((u64)bf16_1(v.w) << 48);
        *(u64*)&ls[k][q*4] = pk;
    }
    __syncthreads();
    #pragma unroll 2
    for (int i = 0; i < 8; ++i) {
        int id = t + 256 * i;                 // 2048 tasks: (col, kg)
        int col = id & 127, kg = id >> 7;     // kg = k-group of 8 (0..15)
        unsigned short v[8];
        #pragma unroll
        for (int j = 0; j < 8; ++j) v[j] = ls[kg*8 + j][col];
        int4 pk;
        pk.x = v[0] | (v[1] << 16); pk.y = v[2] | (v[3] << 16);
        pk.z = v[4] | (v[5] << 16); pk.w = v[6] | (v[7] << 16);
        if (which) {
            // fragment = W2T[c=col][hf = ch*128 + kg*8 ..+7]
            int gp = ch*4 + (kg >> 2);
            int s  = (kg >> 1) & 1;
            int lh = kg & 1;
            int ct = col >> 5;
            int l  = (col & 31) + 32*lh;
            *(int4*)(wt2 + (size_t)e*65536 + gp*4096 + (ct*2 + s)*512 + l*8) = pk;
        } else {
            // fragment = W1T[hf = ch*128+col][C = kg*8 ..+7]
            int gp = ch*4 + (col >> 5);
            int ks = kg >> 1;
            int lh = kg & 1;
            int l  = (col & 31) + 32*lh;
            *(int4*)(wt1 + (size_t)e*65536 + gp*4096 + ks*512 + l*8) = pk;
        }
    }
}

// K1: transpose x -> xfb (token-major bf16), gating, top-2 softmax, lists.
__global__ __launch_bounds__(256) void gate_kernel(
    const float* __restrict__ x, const float* __restrict__ w_g,
    const float* __restrict__ bias, unsigned short* __restrict__ xfb,
    int* __restrict__ list, float* __restrict__ gates,
    int* __restrict__ cnt, float* __restrict__ wsum)
{
    __shared__ float xs[CDIM][65];
    __shared__ float wgs[CDIM][NEXP];
    __shared__ int   cnt_s[NEXP];
    __shared__ float ws_s[NEXP];
    __shared__ int   base_s[NEXP];
    const int t = threadIdx.x;
    const int n0 = blockIdx.x * 64;
    const int b = n0 >> 14;
    const int hw0 = n0 & (HW - 1);

    for (int i = t; i < CDIM * NEXP; i += 256) wgs[i / NEXP][i % NEXP] = w_g[i];
    if (t < NEXP) { cnt_s[t] = 0; ws_s[t] = 0.f; }

    const float* xb = x + (size_t)b * CDIM * HW + hw0;
    #pragma unroll 4
    for (int i = 0; i < 32; ++i) {
        int idx = t + 256 * i;
        int c = idx >> 6, j = idx & 63;
        xs[c][j] = xb[(size_t)c * HW + j];
    }
    __syncthreads();
    unsigned int* xo = (unsigned int*)xfb;
    #pragma unroll 4
    for (int i = 0; i < 16; ++i) {
        int idx = t + 256 * i;
        int tk = idx >> 6, cp = idx & 63;
        xo[(size_t)(n0 + tk) * 64 + cp] = bf16pair(xs[2*cp][tk], xs[2*cp+1][tk]);
    }

    int i0 = 0, i1 = 0, s0 = 0, s1 = 0;
    float g0 = 0.f, g1 = 0.f;
    if (t < 64) {
        float lg[NEXP];
        #pragma unroll
        for (int e = 0; e < NEXP; ++e) lg[e] = bias[b*NEXP + e];
        for (int c = 0; c < CDIM; ++c) {
            float xv = xs[c][t];
            #pragma unroll
            for (int e = 0; e < NEXP; ++e) lg[e] = fmaf(xv, wgs[c][e], lg[e]);
        }
        i0 = 0;
        #pragma unroll
        for (int e = 1; e < NEXP; ++e) if (lg[e] > lg[i0]) i0 = e;
        i1 = (i0 == 0) ? 1 : 0;
        #pragma unroll
        for (int e = 0; e < NEXP; ++e) if (e != i0 && lg[e] > lg[i1]) i1 = e;
        float e1 = expf(lg[i1] - lg[i0]);
        g0 = 1.f / (1.f + e1);
        g1 = e1 * g0;
        s0 = atomicAdd(&cnt_s[i0], 1);
        s1 = atomicAdd(&cnt_s[i1], 1);
        atomicAdd(&ws_s[i0], g0);
        atomicAdd(&ws_s[i1], g1);
    }
    __syncthreads();
    if (t < NEXP) {
        base_s[t] = atomicAdd(&cnt[t], cnt_s[t]);
        atomicAdd(&wsum[t], ws_s[t]);
    }
    __syncthreads();
    if (t < 64) {
        int n = n0 + t;
        list[i0 * NTOK + base_s[i0] + s0] = 2 * n;
        list[i1 * NTOK + base_s[i1] + s1] = 2 * n + 1;
        gates[2 * n]     = g0;
        gates[2 * n + 1] = g1;
    }
}

// K2: balance loss
__global__ void loss_kernel(const int* __restrict__ cnt,
                            const float* __restrict__ wsum,
                            float* __restrict__ out_loss)
{
    if (threadIdx.x == 0 && blockIdx.x == 0) {
        float mw = 0.f, mc = 0.f;
        for (int e = 0; e < NEXP; ++e) { mw += wsum[e]; mc += (float)cnt[e]; }
        mw /= NEXP; mc /= NEXP;
        float vw = 0.f, vc = 0.f;
        for (int e = 0; e < NEXP; ++e) {
            float dw = wsum[e] - mw, dc = (float)cnt[e] - mc;
            vw += dw * dw; vc += dc * dc;
        }
        vw /= (NEXP - 1); vc /= (NEXP - 1);
        out_loss[0] = vw / (mw * mw + 1e-10f) + vc / (mc * mc + 1e-10f);
    }
}

// K3: barrier-free, LDS-free MFMA expert MLP with COALESCED weight streams.
// 1 wave per block, 64 tokens (two 32-token groups share every weight frag);
// weights in fragment-order global layout -> every weight load is
// base + l*16 (8 cache lines/inst, the minimum). Software pipeline:
// W1(gp+1) issued under gelu+GEMM2; W2(gp) issued under gelu.
__global__ __launch_bounds__(64, 2) void expert_kernel(
    const unsigned short* __restrict__ xfb, const int* __restrict__ list,
    const int* __restrict__ cnt, const float* __restrict__ gates,
    const unsigned short* __restrict__ wt1, const unsigned short* __restrict__ wt2,
    const float* __restrict__ fc1_b, const float* __restrict__ fc2_b,
    unsigned short* __restrict__ outbuf)
{
    const int e = blockIdx.x;
    const int ne = cnt[e];
    const int base = blockIdx.y * 64;
    if (base >= ne) return;
    const int l = threadIdx.x;
    const int l31 = l & 31, lh = l >> 5;
    const bool islo = (l < 32);

    int r = base + l;
    int a = (r < ne) ? list[e*NTOK + r] : -1;
    float g = (a >= 0) ? gates[a] : 0.f;
    int tok = (a >= 0) ? (a >> 1) : 0;

    int tkA = __shfl(tok, l31);        // group A: token for col l31
    int tkB = __shfl(tok, 32 + l31);   // group B

    // X B-fragments: lane holds X[k = ks*16 + lh*8 ..+7][tok]
    short8 afrA[8], afrB[8];
    {
        const unsigned short* xrA = xfb + (size_t)tkA*128 + lh*8;
        const unsigned short* xrB = xfb + (size_t)tkB*128 + lh*8;
        #pragma unroll
        for (int ks = 0; ks < 8; ++ks) {
            afrA[ks] = *(const short8*)(xrA + ks*16);
            afrB[ks] = *(const short8*)(xrB + ks*16);
        }
    }

    f32x16 zz;
    #pragma unroll
    for (int i = 0; i < 16; ++i) zz[i] = 0.0f;
    f32x16 oA0 = zz, oA1 = zz, oA2 = zz, oA3 = zz;
    f32x16 oB0 = zz, oB1 = zz, oB2 = zz, oB3 = zz;

    const unsigned short* w1e = wt1 + ((size_t)e << 16) + l*8;
    const unsigned short* w2e = wt2 + ((size_t)e << 16) + l*8;

    // preload W1(gp=0): fully coalesced 1-KB blocks
    short8 wf[8];
    #pragma unroll
    for (int ks = 0; ks < 8; ++ks)
        wf[ks] = *(const short8*)(w1e + ks*512);

    for (int gp = 0; gp < 16; ++gp) {         // 32-hf chunks
        // GEMM1: C1[hf 32][tok 32] for both groups (wf reused)
        f32x16 c1a = zz, c1b = zz;
        #pragma unroll
        for (int ks = 0; ks < 8; ++ks) {
            c1a = MFMA_B(wf[ks], afrA[ks], c1a);
            c1b = MFMA_B(wf[ks], afrB[ks], c1b);
        }
        // issue W2(gp) -- covered by gelu/pack below
        short8 w2r[8];
        {
            const unsigned short* wb = w2e + gp*4096;
            #pragma unroll
            for (int i = 0; i < 8; ++i)
                w2r[i] = *(const short8*)(wb + i*512);
        }
        // issue W1(gp+1) -- covered by gelu + GEMM2 + loop-back
        if (gp < 15) {
            const unsigned short* wb = w1e + (gp + 1)*4096;
            #pragma unroll
            for (int ks = 0; ks < 8; ++ks)
                wf[ks] = *(const short8*)(wb + ks*512);
        }

        // bias + gelu + pack + cross-half exchange -> pa frags (r7-verified)
        const float* bb = fc1_b + (size_t)e*HFDIM + gp*32 + 4*lh;
        float4 b0 = *(const float4*)(bb);
        float4 b1 = *(const float4*)(bb + 8);
        float4 b2 = *(const float4*)(bb + 16);
        float4 b3 = *(const float4*)(bb + 24);
        float bias[16] = {b0.x, b0.y, b0.z, b0.w, b1.x, b1.y, b1.z, b1.w,
                          b2.x, b2.y, b2.z, b2.w, b3.x, b3.y, b3.z, b3.w};
        unsigned int prA[8], prB[8];
        #pragma unroll
        for (int i = 0; i < 8; ++i) {
            prA[i] = bf16pair(gelu_f(c1a[2*i]   + bias[2*i]),
                              gelu_f(c1a[2*i+1] + bias[2*i+1]));
            prB[i] = bf16pair(gelu_f(c1b[2*i]   + bias[2*i]),
                              gelu_f(c1b[2*i+1] + bias[2*i+1]));
        }
        unsigned int axA0 = __shfl_xor(islo ? prA[2] : prA[0], 32);
        unsigned int axA1 = __shfl_xor(islo ? prA[3] : prA[1], 32);
        unsigned int axA2 = __shfl_xor(islo ? prA[6] : prA[4], 32);
        unsigned int axA3 = __shfl_xor(islo ? prA[7] : prA[5], 32);
        short8 paA0 = mk8(islo ? prA[0] : axA0, islo ? prA[1] : axA1,
                          islo ? axA0 : prA[2], islo ? axA1 : prA[3]);
        short8 paA1 = mk8(islo ? prA[4] : axA2, islo ? prA[5] : axA3,
                          islo ? axA2 : prA[6], islo ? axA3 : prA[7]);
        unsigned int axB0 = __shfl_xor(islo ? prB[2] : prB[0], 32);
        unsigned int axB1 = __shfl_xor(islo ? prB[3] : prB[1], 32);
        unsigned int axB2 = __shfl_xor(islo ? prB[6] : prB[4], 32);
        unsigned int axB3 = __shfl_xor(islo ? prB[7] : prB[5], 32);
        short8 paB0 = mk8(islo ? prB[0] : axB0, islo ? prB[1] : axB1,
                          islo ? axB0 : prB[2], islo ? axB1 : prB[3]);
        short8 paB1 = mk8(islo ? prB[4] : axB2, islo ? prB[5] : axB3,
                          islo ? axB2 : prB[6], islo ? axB3 : prB[7]);

        // GEMM2 partial: k-groups gp*2, gp*2+1; w2r reused across groups
        oA0 = MFMA_B(paA0, w2r[0], oA0); oB0 = MFMA_B(paB0, w2r[0], oB0);
        oA0 = MFMA_B(paA1, w2r[1], oA0); oB0 = MFMA_B(paB1, w2r[1], oB0);
        oA1 = MFMA_B(paA0, w2r[2], oA1); oB1 = MFMA_B(paB0, w2r[2], oB1);
        oA1 = MFMA_B(paA1, w2r[3], oA1); oB1 = MFMA_B(paB1, w2r[3], oB1);
        oA2 = MFMA_B(paA0, w2r[4], oA2); oB2 = MFMA_B(paB0, w2r[4], oB2);
        oA2 = MFMA_B(paA1, w2r[5], oA2); oB2 = MFMA_B(paB1, w2r[5], oB2);
        oA3 = MFMA_B(paA0, w2r[6], oA3); oB3 = MFMA_B(paB0, w2r[6], oB3);
        oA3 = MFMA_B(paA1, w2r[7], oA3); oB3 = MFMA_B(paB1, w2r[7], oB3);
    }

    // epilogue: gate * exp(out + fc2_b) -> bf16 scatter to outbuf[a]
    float bc0 = fc2_b[(size_t)e*CDIM + l31];
    float bc1 = fc2_b[(size_t)e*CDIM + 32 + l31];
    float bc2 = fc2_b[(size_t)e*CDIM + 64 + l31];
    float bc3 = fc2_b[(size_t)e*CDIM + 96 + l31];
    #pragma unroll
    for (int rr = 0; rr < 16; ++rr) {
        int crow = (rr & 3) + 8*(rr >> 2) + 4*lh;
        int avA   = __shfl(a, crow);
        float gvA = __shfl(g, crow);
        if (avA >= 0) {
            unsigned short* po = outbuf + (size_t)avA*CDIM + l31;
            po[0]  = (unsigned short)bf16_1(gvA * __expf(oA0[rr] + bc0));
            po[32] = (unsigned short)bf16_1(gvA * __expf(oA1[rr] + bc1));
            po[64] = (unsigned short)bf16_1(gvA * __expf(oA2[rr] + bc2));
            po[96] = (unsigned short)bf16_1(gvA * __expf(oA3[rr] + bc3));
        }
        int avB   = __shfl(a, 32 + crow);
        float gvB = __shfl(g, 32 + crow);
        if (avB >= 0) {
            unsigned short* po = outbuf + (size_t)avB*CDIM + l31;
            po[0]  = (unsigned short)bf16_1(gvB * __expf(oB0[rr] + bc0));
            po[32] = (unsigned short)bf16_1(gvB * __expf(oB1[rr] + bc1));
            po[64] = (unsigned short)bf16_1(gvB * __expf(oB2[rr] + bc2));
            po[96] = (unsigned short)bf16_1(gvB * __expf(oB3[rr] + bc3));
        }
    }
}

// K4: y = log(p0 + p1) from bf16 partials, transpose back to (B,C,H,W)
__global__ __launch_bounds__(256) void combine_kernel(
    const unsigned short* __restrict__ outbuf, float* __restrict__ out)
{
    __shared__ float ys[64][129];
    const int t = threadIdx.x;
    const int n0 = blockIdx.x * 64;
    const int b = n0 >> 14;
    const int hw0 = n0 & (HW - 1);
    #pragma unroll
    for (int i = 0; i < 4; ++i) {
        int idx = t + 256 * i;            // 1024 tasks: token x 16-col group
        int tk = idx >> 4, c8 = (idx & 15) * 8;
        const unsigned short* p = outbuf + (size_t)(n0 + tk) * 256 + c8;
        ushort8v p0 = *(const ushort8v*)p;
        ushort8v p1 = *(const ushort8v*)(p + 128);
        const float EPSL = 2.2204460492503131e-16f;
        #pragma unroll
        for (int j = 0; j < 8; ++j) {
            float v = __uint_as_float((unsigned)p0[j] << 16)
                    + __uint_as_float((unsigned)p1[j] << 16);
            ys[tk][c8 + j] = __logf(v == 0.f ? EPSL : v);
        }
    }
    __syncthreads();
    float* ob = out + (size_t)b * CDIM * HW + hw0;
    #pragma unroll 4
    for (int i = 0; i < 32; ++i) {
        int idx = t + 256 * i;
        int c = idx >> 6;
        int j = idx & 63;
        ob[(size_t)c * HW + j] = ys[j][c];
    }
}

extern "C" void kernel_launch(void* const* d_in, const int* in_sizes, int n_in,
                              void* d_out, int out_size, void* d_ws, size_t ws_size,
                              hipStream_t stream)
{
    const float* x       = (const float*)d_in[0];
    const float* prompt  = (const float*)d_in[1];
    const float* de_cls  = (const float*)d_in[2];
    const float* w_g     = (const float*)d_in[3];
    const float* gboost  = (const float*)d_in[4];
    const float* degra_w = (const float*)d_in[5];
    const float* degra_b = (const float*)d_in[6];
    const float* fc1_w   = (const float*)d_in[7];
    const float* fc1_b   = (const float*)d_in[8];
    const float* fc2_w   = (const float*)d_in[9];
    const float* fc2_b   = (const float*)d_in[10];
    float* out = (float*)d_out;
    char* ws = (char*)d_ws;

    unsigned short* xfb  = (unsigned short*)(ws + OFF_XFB);
    int*   list   = (int*)(ws + OFF_LIST);
    float* gates  = (float*)(ws + OFF_GATES);
    unsigned short* outbuf = (unsigned short*)(ws + OFF_OUTBUF);
    unsigned short* wt1 = (unsigned short*)(ws + OFF_WT1);
    unsigned short* wt2 = (unsigned short*)(ws + OFF_WT2);
    float* bias   = (float*)(ws + OFF_BIAS);
    int*   cnt    = (int*)(ws + OFF_CNT);
    float* wsum   = (float*)(ws + OFF_WSUM);

    prep_kernel<<<1, 64, 0, stream>>>(prompt, de_cls, w_g, gboost, degra_w,
                                      degra_b, bias, cnt, wsum);
    wconv_kernel<<<48, 256, 0, stream>>>(fc1_w, fc2_w, wt1, wt2);
    gate_kernel<<<512, 256, 0, stream>>>(x, w_g, bias, xfb, list, gates, cnt, wsum);
    loss_kernel<<<1, 64, 0, stream>>>(cnt, wsum, out + (size_t)NTOK * CDIM);
    dim3 eg(NEXP, 512);   // 64-token tiles per 1-wave block
    expert_kernel<<<eg, 64, 0, stream>>>(xfb, list, cnt, gates, wt1, wt2,
                                         fc1_b, fc2_b, outbuf);
    combine_kernel<<<512, 256, 0, stream>>>(outbuf, out);
}

// Round 12
// 128.333 us; speedup vs baseline: 1.3415x; 1.0649x over previous
//
#include <hip/hip_runtime.h>
#include <math.h>

#define HW    16384
#define NTOK  32768
#define CDIM  128
#define HFDIM 512
#define NEXP  6

typedef __attribute__((ext_vector_type(8))) short short8;
typedef __attribute__((ext_vector_type(8))) unsigned short ushort8v;
typedef __attribute__((ext_vector_type(16))) float f32x16;
typedef unsigned long long u64;

// workspace byte offsets (256-aligned)
#define OFF_XFB    0UL          // N*128 bf16      = 8,388,608
#define OFF_LIST   8388608UL    // E*N int         =   786,432
#define OFF_GATES  9175040UL    // 2N float        =   262,144
#define OFF_OUTBUF 9437184UL    // 2N*128 bf16     = 16,777,216
#define OFF_WT1    42991616UL   // E*4*16384 bf16  =   786,432  [e][g][hf128][k128] swz16
#define OFF_WT2    43778048UL   // E*8*8192 bf16   =   786,432  [e][gp][c128][k64] swz16-8B
#define OFF_BIAS   44564480UL
#define OFF_CNT    44564736UL
#define OFF_WSUM   44564992UL

__device__ __forceinline__ unsigned int bf16_1(float f) {
    unsigned int u = __float_as_uint(f);
    return (u + 0x7FFFu + ((u >> 16) & 1)) >> 16;
}
__device__ __forceinline__ unsigned int bf16pair(float lo, float hi) {
    return bf16_1(lo) | (bf16_1(hi) << 16);
}
// sigmoid-form gelu: x*sigmoid(1.702x); ~5 VALU inst
__device__ __forceinline__ float gelu_f(float v) {
    return __fdividef(v, 1.0f + __expf(-1.702f * v));
}
__device__ __forceinline__ short8 mk8(unsigned a, unsigned b, unsigned c, unsigned d) {
    union { unsigned u[4]; short8 s; } x;
    x.u[0] = a; x.u[1] = b; x.u[2] = c; x.u[3] = d;
    return x.s;
}
__device__ __forceinline__ short8 mkq(u64 lo, u64 hi) {
    union { u64 q[2]; short8 s; } x;
    x.q[0] = lo; x.q[1] = hi;
    return x.s;
}

#define GLDS16(src, dst) __builtin_amdgcn_global_load_lds( \
    (const __attribute__((address_space(1))) void*)(src),  \
    (__attribute__((address_space(3))) void*)(dst), 16, 0, 0)

__device__ __forceinline__ f32x16 MFMA_B(short8 a, short8 b, f32x16 c) {
    return __builtin_amdgcn_mfma_f32_32x32x16_bf16(a, b, c, 0, 0, 0);
}

// K0: per-batch gating bias + zero atomics (deterministic per call)
__global__ __launch_bounds__(64) void prep_kernel(
    const float* __restrict__ prompt, const float* __restrict__ de_cls,
    const float* __restrict__ w_g, const float* __restrict__ gate_boost,
    const float* __restrict__ degra_w, const float* __restrict__ degra_b,
    float* __restrict__ bias, int* __restrict__ cnt, float* __restrict__ wsum)
{
    int t = threadIdx.x;
    if (t < 2 * NEXP) {
        int b = t / NEXP, e = t % NEXP;
        float acc = 0.f;
        for (int c = 0; c < CDIM; ++c)
            acc = fmaf(prompt[b*CDIM + c], w_g[(CDIM + c)*NEXP + e], acc);
        float db = 0.f;
        for (int d = 0; d < 6; ++d)
            db = fmaf(de_cls[b*6 + d], degra_w[d*NEXP + e], db);
        bias[b*NEXP + e] = acc + gate_boost[0] * (db + degra_b[e]);
    }
    if (t >= 32 && t < 32 + NEXP) cnt[t - 32] = 0;
    if (t >= 40 && t < 40 + NEXP) wsum[t - 40] = 0.f;
}

// Kw: fp32 weights -> bf16, pre-permuted so LINEAR global_load_lds copies
// yield the desired LDS images.
// wt1: [e][g 4][hf 128][k=C 128] rows 256B, 16-slot(16B) XOR (hf&15)   [r7/r8-verified]
// wt2: [e][gp 8][c 128][k=hf 64] rows 128B, 16-granule(8B) XOR (c&15)  [new; b64 reads]
__global__ __launch_bounds__(256) void wconv_kernel(
    const float* __restrict__ fc1_w, const float* __restrict__ fc2_w,
    unsigned short* __restrict__ wt1, unsigned short* __restrict__ wt2)
{
    __shared__ unsigned short ls[128][128];   // [k][col] bf16, 32 KB
    const int bid = blockIdx.x;               // e*8 + which*4 + chunk
    const int e = bid >> 3, which = (bid >> 2) & 1, ch = bid & 3;
    const int t = threadIdx.x;
    #pragma unroll 4
    for (int i = 0; i < 16; ++i) {
        int id = t + 256 * i;                 // 4096 float4 tasks
        int k = id >> 5, q = id & 31;
        // which=0: ls[k=C][col=hf_local]  from fc1_w[e][k][ch*128+col]
        // which=1: ls[k=hf_local][col=c]  from fc2_w[e][ch*128+k][col]
        const float* p = which
            ? (fc2_w + (size_t)e*65536 + (size_t)(ch*128 + k)*128 + q*4)
            : (fc1_w + (size_t)e*65536 + (size_t)k*512 + ch*128 + q*4);
        float4 v = *(const float4*)p;
        u64 pk = (u64)bf16_1(v.x) | ((u64)bf16_1(v.y) << 16)
               | ((u64)bf16_1(v.z) << 32) | ((u64)bf16_1(v.w) << 48);
        *(u64*)&ls[k][q*4] = pk;
    }
    __syncthreads();
    #pragma unroll 2
    for (int i = 0; i < 8; ++i) {
        int id = t + 256 * i;                 // 2048 tasks: (col, kg)
        int col = id & 127, kg = id >> 7;     // kg = k-group of 8 (0..15)
        unsigned short v[8];
        #pragma unroll
        for (int j = 0; j < 8; ++j) v[j] = ls[kg*8 + j][col];
        u64 lo = (u64)v[0] | ((u64)v[1] << 16) | ((u64)v[2] << 32) | ((u64)v[3] << 48);
        u64 hi = (u64)v[4] | ((u64)v[5] << 16) | ((u64)v[6] << 32) | ((u64)v[7] << 48);
        if (which) {
            // window gp' = ch*2 + (kg>>3); window-local k = (kg&7)*8
            // granules g0 = (kg&7)*2, g0+1 (8B each), stored XOR (c&15)
            int h  = kg >> 3;
            int g0 = (kg & 7) * 2;
            unsigned short* d = wt2 + (size_t)e*65536 + (size_t)(ch*2 + h)*8192
                              + (size_t)col*64;
            *(u64*)(d + (((g0    ) ^ (col & 15)) << 2)) = lo;
            *(u64*)(d + (((g0 + 1) ^ (col & 15)) << 2)) = hi;
        } else {
            int4 pk;
            pk.x = (unsigned)(lo & 0xFFFFFFFFu); pk.y = (unsigned)(lo >> 32);
            pk.z = (unsigned)(hi & 0xFFFFFFFFu); pk.w = (unsigned)(hi >> 32);
            *(int4*)(wt1 + (((size_t)(e*4 + ch)) << 14)
                     + (size_t)col*128 + (((kg ^ (col & 15)) & 15) << 3)) = pk;
        }
    }
}

// K1: transpose x -> xfb (token-major bf16), gating, top-2 softmax, lists.
__global__ __launch_bounds__(256) void gate_kernel(
    const float* __restrict__ x, const float* __restrict__ w_g,
    const float* __restrict__ bias, unsigned short* __restrict__ xfb,
    int* __restrict__ list, float* __restrict__ gates,
    int* __restrict__ cnt, float* __restrict__ wsum)
{
    __shared__ float xs[CDIM][65];
    __shared__ float wgs[CDIM][NEXP];
    __shared__ int   cnt_s[NEXP];
    __shared__ float ws_s[NEXP];
    __shared__ int   base_s[NEXP];
    const int t = threadIdx.x;
    const int n0 = blockIdx.x * 64;
    const int b = n0 >> 14;
    const int hw0 = n0 & (HW - 1);

    for (int i = t; i < CDIM * NEXP; i += 256) wgs[i / NEXP][i % NEXP] = w_g[i];
    if (t < NEXP) { cnt_s[t] = 0; ws_s[t] = 0.f; }

    const float* xb = x + (size_t)b * CDIM * HW + hw0;
    #pragma unroll 4
    for (int i = 0; i < 32; ++i) {
        int idx = t + 256 * i;
        int c = idx >> 6, j = idx & 63;
        xs[c][j] = xb[(size_t)c * HW + j];
    }
    __syncthreads();
    unsigned int* xo = (unsigned int*)xfb;
    #pragma unroll 4
    for (int i = 0; i < 16; ++i) {
        int idx = t + 256 * i;
        int tk = idx >> 6, cp = idx & 63;
        xo[(size_t)(n0 + tk) * 64 + cp] = bf16pair(xs[2*cp][tk], xs[2*cp+1][tk]);
    }

    int i0 = 0, i1 = 0, s0 = 0, s1 = 0;
    float g0 = 0.f, g1 = 0.f;
    if (t < 64) {
        float lg[NEXP];
        #pragma unroll
        for (int e = 0; e < NEXP; ++e) lg[e] = bias[b*NEXP + e];
        for (int c = 0; c < CDIM; ++c) {
            float xv = xs[c][t];
            #pragma unroll
            for (int e = 0; e < NEXP; ++e) lg[e] = fmaf(xv, wgs[c][e], lg[e]);
        }
        i0 = 0;
        #pragma unroll
        for (int e = 1; e < NEXP; ++e) if (lg[e] > lg[i0]) i0 = e;
        i1 = (i0 == 0) ? 1 : 0;
        #pragma unroll
        for (int e = 0; e < NEXP; ++e) if (e != i0 && lg[e] > lg[i1]) i1 = e;
        float e1 = expf(lg[i1] - lg[i0]);
        g0 = 1.f / (1.f + e1);
        g1 = e1 * g0;
        s0 = atomicAdd(&cnt_s[i0], 1);
        s1 = atomicAdd(&cnt_s[i1], 1);
        atomicAdd(&ws_s[i0], g0);
        atomicAdd(&ws_s[i1], g1);
    }
    __syncthreads();
    if (t < NEXP) {
        base_s[t] = atomicAdd(&cnt[t], cnt_s[t]);
        atomicAdd(&wsum[t], ws_s[t]);
    }
    __syncthreads();
    if (t < 64) {
        int n = n0 + t;
        list[i0 * NTOK + base_s[i0] + s0] = 2 * n;
        list[i1 * NTOK + base_s[i1] + s1] = 2 * n + 1;
        gates[2 * n]     = g0;
        gates[2 * n + 1] = g1;
    }
}

// K2: balance loss
__global__ void loss_kernel(const int* __restrict__ cnt,
                            const float* __restrict__ wsum,
                            float* __restrict__ out_loss)
{
    if (threadIdx.x == 0 && blockIdx.x == 0) {
        float mw = 0.f, mc = 0.f;
        for (int e = 0; e < NEXP; ++e) { mw += wsum[e]; mc += (float)cnt[e]; }
        mw /= NEXP; mc /= NEXP;
        float vw = 0.f, vc = 0.f;
        for (int e = 0; e < NEXP; ++e) {
            float dw = wsum[e] - mw, dc = (float)cnt[e] - mc;
            vw += dw * dw; vc += dc * dc;
        }
        vw /= (NEXP - 1); vc /= (NEXP - 1);
        out_loss[0] = vw / (mw * mw + 1e-10f) + vc / (mc * mc + 1e-10f);
    }
}

// K3: r6's delivery (global_load_lds staged weights, multi-block/CU overlap)
// + r7's in-reg hid (no hs buffer) + conflict-free LDS by construction.
// 2-wave / 64-token blocks (1026 working blocks); wave w owns tokens
// base + w*32 .. +31 end-to-end. LDS = 32 KB (w1c 16K swz16-b128 +
// w2c 16K swz16-8B read as ds_read_b64 pairs) -> 5 blocks/CU by LDS.
__global__ __launch_bounds__(128, 2) void expert_kernel(
    const unsigned short* __restrict__ xfb, const int* __restrict__ list,
    const int* __restrict__ cnt, const float* __restrict__ gates,
    const unsigned short* __restrict__ wt1, const unsigned short* __restrict__ wt2,
    const float* __restrict__ fc1_b, const float* __restrict__ fc2_b,
    unsigned short* __restrict__ outbuf)
{
    __shared__ unsigned short w1c[8192];   // 16 KB [64 hf][128 k]  swz16 (16B slots)
    __shared__ unsigned short w2c[8192];   // 16 KB [128 c][64 k]   swz16 (8B granules)
    const int e = blockIdx.x;
    const int ne = cnt[e];
    const int base = blockIdx.y * 64;
    if (base >= ne) return;
    const int t = threadIdx.x;
    const int w = t >> 6, l = t & 63;
    const int l31 = l & 31, lh = l >> 5;
    const bool islo = (l < 32);

    // wave w's tokens; lanes l and l+32 intentionally load the same entry
    int r = base + w*32 + l31;
    int a = (r < ne) ? list[e*NTOK + r] : -1;
    float g = (a >= 0) ? gates[a] : 0.f;
    int tok = (a >= 0) ? (a >> 1) : 0;

    // X B-fragments: lane holds X[k = ks*16 + lh*8 ..+7][tok = l31's token]
    short8 afr[8];
    {
        const unsigned short* xr = xfb + (size_t)tok*128 + lh*8;
        #pragma unroll
        for (int ks = 0; ks < 8; ++ks)
            afr[ks] = *(const short8*)(xr + ks*16);
    }

    f32x16 zz;
    #pragma unroll
    for (int i = 0; i < 16; ++i) zz[i] = 0.0f;
    f32x16 o0 = zz, o1 = zz, o2 = zz, o3 = zz;

    for (int gp = 0; gp < 8; ++gp) {          // 64-hf windows
        // stage w1c (16KB) + w2c (16KB); wave w fills its half of each
        {
            const unsigned short* s1 = wt1 + (((size_t)(e*4 + (gp >> 1))) << 14)
                                     + (gp & 1)*8192 + w*4096 + l*8;
            const unsigned short* s2 = wt2 + (size_t)e*65536 + (size_t)gp*8192
                                     + w*4096 + l*8;
            #pragma unroll
            for (int i = 0; i < 8; ++i)
                GLDS16(s1 + i*512, &w1c[w*4096 + i*512]);
            #pragma unroll
            for (int i = 0; i < 8; ++i)
                GLDS16(s2 + i*512, &w2c[w*4096 + i*512]);
        }
        __syncthreads();

        #pragma unroll
        for (int ch = 0; ch < 2; ++ch) {      // 32-hf chunks of the window
            // GEMM1: C1[hf 32][tok 32], k = C = 128
            f32x16 c1 = zz;
            {
                int arow = ch*32 + l31;
                #pragma unroll
                for (int ks = 0; ks < 8; ++ks) {
                    int kk = ks*2 + lh;
                    short8 wf = *(const short8*)((const char*)w1c + arow*256
                                 + (((kk ^ (arow & 15)) & 15) << 4));
                    c1 = MFMA_B(wf, afr[ks], c1);
                }
            }
            // bias + gelu + pack + cross-half exchange -> pa frags (r7-verified)
            const float* bb = fc1_b + (size_t)e*HFDIM + gp*64 + ch*32 + 4*lh;
            float4 b0 = *(const float4*)(bb);
            float4 b1 = *(const float4*)(bb + 8);
            float4 b2 = *(const float4*)(bb + 16);
            float4 b3 = *(const float4*)(bb + 24);
            float bias[16] = {b0.x, b0.y, b0.z, b0.w, b1.x, b1.y, b1.z, b1.w,
                              b2.x, b2.y, b2.z, b2.w, b3.x, b3.y, b3.z, b3.w};
            unsigned int pr[8];
            #pragma unroll
            for (int i = 0; i < 8; ++i) {
                pr[i] = bf16pair(gelu_f(c1[2*i]   + bias[2*i]),
                                 gelu_f(c1[2*i+1] + bias[2*i+1]));
            }
            unsigned int rx0 = __shfl_xor(islo ? pr[2] : pr[0], 32);
            unsigned int rx1 = __shfl_xor(islo ? pr[3] : pr[1], 32);
            unsigned int rx2 = __shfl_xor(islo ? pr[6] : pr[4], 32);
            unsigned int rx3 = __shfl_xor(islo ? pr[7] : pr[5], 32);
            short8 pa0 = mk8(islo ? pr[0] : rx0, islo ? pr[1] : rx1,
                             islo ? rx0 : pr[2], islo ? rx1 : pr[3]);
            short8 pa1 = mk8(islo ? pr[4] : rx2, islo ? pr[5] : rx3,
                             islo ? rx2 : pr[6], islo ? rx3 : pr[7]);

            // GEMM2 partial: window k-groups kg = ch*2 (pa0), ch*2+1 (pa1).
            // B-frags from w2c via paired ds_read_b64 (2-way banks = free).
            #pragma unroll
            for (int ct = 0; ct < 4; ++ct) {
                int c = ct*32 + l31;
                const char* rb = (const char*)w2c + c*128;
                int xm = c & 15;
                int ga = ch*8 + lh*2;         // granules for kg=ch*2
                int gb = ch*8 + 4 + lh*2;     // granules for kg=ch*2+1
                u64 q0 = *(const u64*)(rb + (((ga    ) ^ xm) << 3));
                u64 q1 = *(const u64*)(rb + (((ga + 1) ^ xm) << 3));
                u64 q2 = *(const u64*)(rb + (((gb    ) ^ xm) << 3));
                u64 q3 = *(const u64*)(rb + (((gb + 1) ^ xm) << 3));
                short8 bf0 = mkq(q0, q1);
                short8 bf1 = mkq(q2, q3);
                if (ct == 0) { o0 = MFMA_B(pa0, bf0, o0); o0 = MFMA_B(pa1, bf1, o0); }
                else if (ct == 1) { o1 = MFMA_B(pa0, bf0, o1); o1 = MFMA_B(pa1, bf1, o1); }
                else if (ct == 2) { o2 = MFMA_B(pa0, bf0, o2); o2 = MFMA_B(pa1, bf1, o2); }
                else              { o3 = MFMA_B(pa0, bf0, o3); o3 = MFMA_B(pa1, bf1, o3); }
            }
        }
        __syncthreads();   // all LDS reads done -> safe to restage
    }

    // epilogue: gate * exp(out + fc2_b) -> bf16 scatter to outbuf[a]
    float bc0 = fc2_b[(size_t)e*CDIM + l31];
    float bc1 = fc2_b[(size_t)e*CDIM + 32 + l31];
    float bc2 = fc2_b[(size_t)e*CDIM + 64 + l31];
    float bc3 = fc2_b[(size_t)e*CDIM + 96 + l31];
    #pragma unroll
    for (int rr = 0; rr < 16; ++rr) {
        int crow = (rr & 3) + 8*(rr >> 2) + 4*lh;
        int av   = __shfl(a, crow);
        float gv = __shfl(g, crow);
        if (av < 0) continue;
        unsigned short* po = outbuf + (size_t)av*CDIM + l31;
        po[0]  = (unsigned short)bf16_1(gv * __expf(o0[rr] + bc0));
        po[32] = (unsigned short)bf16_1(gv * __expf(o1[rr] + bc1));
        po[64] = (unsigned short)bf16_1(gv * __expf(o2[rr] + bc2));
        po[96] = (unsigned short)bf16_1(gv * __expf(o3[rr] + bc3));
    }
}

// K4: y = log(p0 + p1) from bf16 partials, transpose back to (B,C,H,W)
__global__ __launch_bounds__(256) void combine_kernel(
    const unsigned short* __restrict__ outbuf, float* __restrict__ out)
{
    __shared__ float ys[64][129];
    const int t = threadIdx.x;
    const int n0 = blockIdx.x * 64;
    const int b = n0 >> 14;
    const int hw0 = n0 & (HW - 1);
    #pragma unroll
    for (int i = 0; i < 4; ++i) {
        int idx = t + 256 * i;            // 1024 tasks: token x 16-col group
        int tk = idx >> 4, c8 = (idx & 15) * 8;
        const unsigned short* p = outbuf + (size_t)(n0 + tk) * 256 + c8;
        ushort8v p0 = *(const ushort8v*)p;
        ushort8v p1 = *(const ushort8v*)(p + 128);
        const float EPSL = 2.2204460492503131e-16f;
        #pragma unroll
        for (int j = 0; j < 8; ++j) {
            float v = __uint_as_float((unsigned)p0[j] << 16)
                    + __uint_as_float((unsigned)p1[j] << 16);
            ys[tk][c8 + j] = __logf(v == 0.f ? EPSL : v);
        }
    }
    __syncthreads();
    float* ob = out + (size_t)b * CDIM * HW + hw0;
    #pragma unroll 4
    for (int i = 0; i < 32; ++i) {
        int idx = t + 256 * i;
        int c = idx >> 6;
        int j = idx & 63;
        ob[(size_t)c * HW + j] = ys[j][c];
    }
}

extern "C" void kernel_launch(void* const* d_in, const int* in_sizes, int n_in,
                              void* d_out, int out_size, void* d_ws, size_t ws_size,
                              hipStream_t stream)
{
    const float* x       = (const float*)d_in[0];
    const float* prompt  = (const float*)d_in[1];
    const float* de_cls  = (const float*)d_in[2];
    const float* w_g     = (const float*)d_in[3];
    const float* gboost  = (const float*)d_in[4];
    const float* degra_w = (const float*)d_in[5];
    const float* degra_b = (const float*)d_in[6];
    const float* fc1_w   = (const float*)d_in[7];
    const float* fc1_b   = (const float*)d_in[8];
    const float* fc2_w   = (const float*)d_in[9];
    const float* fc2_b   = (const float*)d_in[10];
    float* out = (float*)d_out;
    char* ws = (char*)d_ws;

    unsigned short* xfb  = (unsigned short*)(ws + OFF_XFB);
    int*   list   = (int*)(ws + OFF_LIST);
    float* gates  = (float*)(ws + OFF_GATES);
    unsigned short* outbuf = (unsigned short*)(ws + OFF_OUTBUF);
    unsigned short* wt1 = (unsigned short*)(ws + OFF_WT1);
    unsigned short* wt2 = (unsigned short*)(ws + OFF_WT2);
    float* bias   = (float*)(ws + OFF_BIAS);
    int*   cnt    = (int*)(ws + OFF_CNT);
    float* wsum   = (float*)(ws + OFF_WSUM);

    prep_kernel<<<1, 64, 0, stream>>>(prompt, de_cls, w_g, gboost, degra_w,
                                      degra_b, bias, cnt, wsum);
    wconv_kernel<<<48, 256, 0, stream>>>(fc1_w, fc2_w, wt1, wt2);
    gate_kernel<<<512, 256, 0, stream>>>(x, w_g, bias, xfb, list, gates, cnt, wsum);
    loss_kernel<<<1, 64, 0, stream>>>(cnt, wsum, out + (size_t)NTOK * CDIM);
    dim3 eg(NEXP, 512);   // 64-token / 2-wave blocks
    expert_kernel<<<eg, 128, 0, stream>>>(xfb, list, cnt, gates, wt1, wt2,
                                          fc1_b, fc2_b, outbuf);
    combine_kernel<<<512, 256, 0, stream>>>(outbuf, out);
}

// Round 13
// 118.625 us; speedup vs baseline: 1.4513x; 1.0818x over previous
//
#include <hip/hip_runtime.h>
#include <math.h>

#define HW    16384
#define NTOK  32768
#define CDIM  128
#define HFDIM 512
#define NEXP  6

typedef __attribute__((ext_vector_type(8))) short short8;
typedef __attribute__((ext_vector_type(8))) unsigned short ushort8v;
typedef __attribute__((ext_vector_type(16))) float f32x16;
typedef unsigned long long u64;

// workspace byte offsets (256-aligned)
#define OFF_XFB    0UL          // N*128 bf16      = 8,388,608
#define OFF_LIST   8388608UL    // E*N int         =   786,432
#define OFF_GATES  9175040UL    // 2N float        =   262,144
#define OFF_OUTBUF 9437184UL    // 2N*128 bf16     = 16,777,216
#define OFF_WT1    42991616UL   // E*4*16384 bf16  =   786,432  [e][g][hf128][k128] swz16
#define OFF_WT2    43778048UL   // E*8*8192 bf16   =   786,432  [e][gp][c128][k64] swz16-8B
#define OFF_BIAS   44564480UL
#define OFF_CNT    44564736UL
#define OFF_WSUM   44564992UL

__device__ __forceinline__ unsigned int bf16_1(float f) {
    unsigned int u = __float_as_uint(f);
    return (u + 0x7FFFu + ((u >> 16) & 1)) >> 16;
}
__device__ __forceinline__ unsigned int bf16pair(float lo, float hi) {
    return bf16_1(lo) | (bf16_1(hi) << 16);
}
// sigmoid-form gelu: x*sigmoid(1.702x); ~5 VALU inst
__device__ __forceinline__ float gelu_f(float v) {
    return __fdividef(v, 1.0f + __expf(-1.702f * v));
}
__device__ __forceinline__ short8 mk8(unsigned a, unsigned b, unsigned c, unsigned d) {
    union { unsigned u[4]; short8 s; } x;
    x.u[0] = a; x.u[1] = b; x.u[2] = c; x.u[3] = d;
    return x.s;
}
__device__ __forceinline__ short8 mkq(u64 lo, u64 hi) {
    union { u64 q[2]; short8 s; } x;
    x.q[0] = lo; x.q[1] = hi;
    return x.s;
}

#define GLDS16(src, dst) __builtin_amdgcn_global_load_lds( \
    (const __attribute__((address_space(1))) void*)(src),  \
    (__attribute__((address_space(3))) void*)(dst), 16, 0, 0)

__device__ __forceinline__ f32x16 MFMA_B(short8 a, short8 b, f32x16 c) {
    return __builtin_amdgcn_mfma_f32_32x32x16_bf16(a, b, c, 0, 0, 0);
}

// K0: per-batch gating bias + zero atomics (deterministic per call)
__global__ __launch_bounds__(64) void prep_kernel(
    const float* __restrict__ prompt, const float* __restrict__ de_cls,
    const float* __restrict__ w_g, const float* __restrict__ gate_boost,
    const float* __restrict__ degra_w, const float* __restrict__ degra_b,
    float* __restrict__ bias, int* __restrict__ cnt, float* __restrict__ wsum)
{
    int t = threadIdx.x;
    if (t < 2 * NEXP) {
        int b = t / NEXP, e = t % NEXP;
        float acc = 0.f;
        for (int c = 0; c < CDIM; ++c)
            acc = fmaf(prompt[b*CDIM + c], w_g[(CDIM + c)*NEXP + e], acc);
        float db = 0.f;
        for (int d = 0; d < 6; ++d)
            db = fmaf(de_cls[b*6 + d], degra_w[d*NEXP + e], db);
        bias[b*NEXP + e] = acc + gate_boost[0] * (db + degra_b[e]);
    }
    if (t >= 32 && t < 32 + NEXP) cnt[t - 32] = 0;
    if (t >= 40 && t < 40 + NEXP) wsum[t - 40] = 0.f;
}

// Kw: fp32 weights -> bf16, pre-permuted so LINEAR global_load_lds copies
// yield the desired LDS images.  (r12-verified)
// wt1: [e][g 4][hf 128][k=C 128] rows 256B, 16-slot(16B) XOR (hf&15)
// wt2: [e][gp 8][c 128][k=hf 64] rows 128B, 16-granule(8B) XOR (c&15)
__global__ __launch_bounds__(256) void wconv_kernel(
    const float* __restrict__ fc1_w, const float* __restrict__ fc2_w,
    unsigned short* __restrict__ wt1, unsigned short* __restrict__ wt2)
{
    __shared__ unsigned short ls[128][128];   // [k][col] bf16, 32 KB
    const int bid = blockIdx.x;               // e*8 + which*4 + chunk
    const int e = bid >> 3, which = (bid >> 2) & 1, ch = bid & 3;
    const int t = threadIdx.x;
    #pragma unroll 4
    for (int i = 0; i < 16; ++i) {
        int id = t + 256 * i;                 // 4096 float4 tasks
        int k = id >> 5, q = id & 31;
        const float* p = which
            ? (fc2_w + (size_t)e*65536 + (size_t)(ch*128 + k)*128 + q*4)
            : (fc1_w + (size_t)e*65536 + (size_t)k*512 + ch*128 + q*4);
        float4 v = *(const float4*)p;
        u64 pk = (u64)bf16_1(v.x) | ((u64)bf16_1(v.y) << 16)
               | ((u64)bf16_1(v.z) << 32) | ((u64)bf16_1(v.w) << 48);
        *(u64*)&ls[k][q*4] = pk;
    }
    __syncthreads();
    #pragma unroll 2
    for (int i = 0; i < 8; ++i) {
        int id = t + 256 * i;                 // 2048 tasks: (col, kg)
        int col = id & 127, kg = id >> 7;     // kg = k-group of 8 (0..15)
        unsigned short v[8];
        #pragma unroll
        for (int j = 0; j < 8; ++j) v[j] = ls[kg*8 + j][col];
        u64 lo = (u64)v[0] | ((u64)v[1] << 16) | ((u64)v[2] << 32) | ((u64)v[3] << 48);
        u64 hi = (u64)v[4] | ((u64)v[5] << 16) | ((u64)v[6] << 32) | ((u64)v[7] << 48);
        if (which) {
            int h  = kg >> 3;
            int g0 = (kg & 7) * 2;
            unsigned short* d = wt2 + (size_t)e*65536 + (size_t)(ch*2 + h)*8192
                              + (size_t)col*64;
            *(u64*)(d + (((g0    ) ^ (col & 15)) << 2)) = lo;
            *(u64*)(d + (((g0 + 1) ^ (col & 15)) << 2)) = hi;
        } else {
            int4 pk;
            pk.x = (unsigned)(lo & 0xFFFFFFFFu); pk.y = (unsigned)(lo >> 32);
            pk.z = (unsigned)(hi & 0xFFFFFFFFu); pk.w = (unsigned)(hi >> 32);
            *(int4*)(wt1 + (((size_t)(e*4 + ch)) << 14)
                     + (size_t)col*128 + (((kg ^ (col & 15)) & 15) << 3)) = pk;
        }
    }
}

// K1: transpose x -> xfb (token-major bf16), gating, top-2 softmax, lists.
__global__ __launch_bounds__(256) void gate_kernel(
    const float* __restrict__ x, const float* __restrict__ w_g,
    const float* __restrict__ bias, unsigned short* __restrict__ xfb,
    int* __restrict__ list, float* __restrict__ gates,
    int* __restrict__ cnt, float* __restrict__ wsum)
{
    __shared__ float xs[CDIM][65];
    __shared__ float wgs[CDIM][NEXP];
    __shared__ int   cnt_s[NEXP];
    __shared__ float ws_s[NEXP];
    __shared__ int   base_s[NEXP];
    const int t = threadIdx.x;
    const int n0 = blockIdx.x * 64;
    const int b = n0 >> 14;
    const int hw0 = n0 & (HW - 1);

    for (int i = t; i < CDIM * NEXP; i += 256) wgs[i / NEXP][i % NEXP] = w_g[i];
    if (t < NEXP) { cnt_s[t] = 0; ws_s[t] = 0.f; }

    const float* xb = x + (size_t)b * CDIM * HW + hw0;
    #pragma unroll 4
    for (int i = 0; i < 32; ++i) {
        int idx = t + 256 * i;
        int c = idx >> 6, j = idx & 63;
        xs[c][j] = xb[(size_t)c * HW + j];
    }
    __syncthreads();
    unsigned int* xo = (unsigned int*)xfb;
    #pragma unroll 4
    for (int i = 0; i < 16; ++i) {
        int idx = t + 256 * i;
        int tk = idx >> 6, cp = idx & 63;
        xo[(size_t)(n0 + tk) * 64 + cp] = bf16pair(xs[2*cp][tk], xs[2*cp+1][tk]);
    }

    int i0 = 0, i1 = 0, s0 = 0, s1 = 0;
    float g0 = 0.f, g1 = 0.f;
    if (t < 64) {
        float lg[NEXP];
        #pragma unroll
        for (int e = 0; e < NEXP; ++e) lg[e] = bias[b*NEXP + e];
        for (int c = 0; c < CDIM; ++c) {
            float xv = xs[c][t];
            #pragma unroll
            for (int e = 0; e < NEXP; ++e) lg[e] = fmaf(xv, wgs[c][e], lg[e]);
        }
        i0 = 0;
        #pragma unroll
        for (int e = 1; e < NEXP; ++e) if (lg[e] > lg[i0]) i0 = e;
        i1 = (i0 == 0) ? 1 : 0;
        #pragma unroll
        for (int e = 0; e < NEXP; ++e) if (e != i0 && lg[e] > lg[i1]) i1 = e;
        float e1 = expf(lg[i1] - lg[i0]);
        g0 = 1.f / (1.f + e1);
        g1 = e1 * g0;
        s0 = atomicAdd(&cnt_s[i0], 1);
        s1 = atomicAdd(&cnt_s[i1], 1);
        atomicAdd(&ws_s[i0], g0);
        atomicAdd(&ws_s[i1], g1);
    }
    __syncthreads();
    if (t < NEXP) {
        base_s[t] = atomicAdd(&cnt[t], cnt_s[t]);
        atomicAdd(&wsum[t], ws_s[t]);
    }
    __syncthreads();
    if (t < 64) {
        int n = n0 + t;
        list[i0 * NTOK + base_s[i0] + s0] = 2 * n;
        list[i1 * NTOK + base_s[i1] + s1] = 2 * n + 1;
        gates[2 * n]     = g0;
        gates[2 * n + 1] = g1;
    }
}

// K2: balance loss
__global__ void loss_kernel(const int* __restrict__ cnt,
                            const float* __restrict__ wsum,
                            float* __restrict__ out_loss)
{
    if (threadIdx.x == 0 && blockIdx.x == 0) {
        float mw = 0.f, mc = 0.f;
        for (int e = 0; e < NEXP; ++e) { mw += wsum[e]; mc += (float)cnt[e]; }
        mw /= NEXP; mc /= NEXP;
        float vw = 0.f, vc = 0.f;
        for (int e = 0; e < NEXP; ++e) {
            float dw = wsum[e] - mw, dc = (float)cnt[e] - mc;
            vw += dw * dw; vc += dc * dc;
        }
        vw /= (NEXP - 1); vc /= (NEXP - 1);
        out_loss[0] = vw / (mw * mw + 1e-10f) + vc / (mc * mc + 1e-10f);
    }
}

// K3: r12 + T3/T4 pipeline: double-buffered weight windows, counted
// s_waitcnt vmcnt(8) (next window's 8 loads stay in flight across compute),
// raw s_barrier (no vmcnt(0) drain in the loop). 128-token / 4-wave blocks
// (513 working, ~2/CU); LDS = 2x(16K w1 + 16K w2) = 64 KB.
// Sync proof: each wave's vmcnt(8) retires its OWN current-window loads
// before bar1 -> after bar1 whole buffer valid. stage(gp+1) writes
// buf[(gp+1)&1], last read in compute(gp-1), separated by bar2(gp-1);
// every ds_read completes before bar2 (each feeds an MFMA before it).
__global__ __launch_bounds__(256, 2) void expert_kernel(
    const unsigned short* __restrict__ xfb, const int* __restrict__ list,
    const int* __restrict__ cnt, const float* __restrict__ gates,
    const unsigned short* __restrict__ wt1, const unsigned short* __restrict__ wt2,
    const float* __restrict__ fc1_b, const float* __restrict__ fc2_b,
    unsigned short* __restrict__ outbuf)
{
    __shared__ unsigned short w1c[2][8192];   // 2 x 16 KB [64 hf][128 k] swz16
    __shared__ unsigned short w2c[2][8192];   // 2 x 16 KB [128 c][64 k]  swz16-8B
    const int e = blockIdx.x;
    const int ne = cnt[e];
    const int base = blockIdx.y * 128;
    if (base >= ne) return;
    const int t = threadIdx.x;
    const int w = t >> 6, l = t & 63;
    const int l31 = l & 31, lh = l >> 5;
    const bool islo = (l < 32);

    // wave w owns tokens base + w*32 .. +31 (both lane halves same entry)
    int r = base + w*32 + l31;
    int a = (r < ne) ? list[e*NTOK + r] : -1;
    float g = (a >= 0) ? gates[a] : 0.f;
    int tok = (a >= 0) ? (a >> 1) : 0;

    // X B-fragments: lane holds X[k = ks*16 + lh*8 ..+7][tok]
    short8 afr[8];
    {
        const unsigned short* xr = xfb + (size_t)tok*128 + lh*8;
        #pragma unroll
        for (int ks = 0; ks < 8; ++ks)
            afr[ks] = *(const short8*)(xr + ks*16);
    }

    // stage window gp into buffer buf: waves 0-1 fill w1c, waves 2-3 fill w2c
    auto STAGE = [&](int gp, int buf) {
        if (w < 2) {
            const unsigned short* s1 = wt1 + (((size_t)(e*4 + (gp >> 1))) << 14)
                                     + (gp & 1)*8192 + w*4096 + l*8;
            #pragma unroll
            for (int i = 0; i < 8; ++i)
                GLDS16(s1 + i*512, &w1c[buf][w*4096 + i*512]);
        } else {
            const unsigned short* s2 = wt2 + (size_t)e*65536 + (size_t)gp*8192
                                     + (w - 2)*4096 + l*8;
            #pragma unroll
            for (int i = 0; i < 8; ++i)
                GLDS16(s2 + i*512, &w2c[buf][(w - 2)*4096 + i*512]);
        }
    };

    f32x16 zz;
    #pragma unroll
    for (int i = 0; i < 16; ++i) zz[i] = 0.0f;
    f32x16 o0 = zz, o1 = zz, o2 = zz, o3 = zz;

    STAGE(0, 0);

    for (int gp = 0; gp < 8; ++gp) {          // 64-hf windows
        const int cur = gp & 1;
        if (gp < 7) {
            STAGE(gp + 1, cur ^ 1);
            asm volatile("s_waitcnt vmcnt(8)" ::: "memory");
        } else {
            asm volatile("s_waitcnt vmcnt(0)" ::: "memory");
        }
        __builtin_amdgcn_s_barrier();

        #pragma unroll
        for (int ch = 0; ch < 2; ++ch) {      // 32-hf chunks of the window
            // GEMM1: C1[hf 32][tok 32], k = C = 128
            f32x16 c1 = zz;
            {
                int arow = ch*32 + l31;
                #pragma unroll
                for (int ks = 0; ks < 8; ++ks) {
                    int kk = ks*2 + lh;
                    short8 wf = *(const short8*)((const char*)w1c[cur] + arow*256
                                 + (((kk ^ (arow & 15)) & 15) << 4));
                    c1 = MFMA_B(wf, afr[ks], c1);
                }
            }
            // bias + gelu + pack + cross-half exchange -> pa frags (r7-verified)
            const float* bb = fc1_b + (size_t)e*HFDIM + gp*64 + ch*32 + 4*lh;
            float4 b0 = *(const float4*)(bb);
            float4 b1 = *(const float4*)(bb + 8);
            float4 b2 = *(const float4*)(bb + 16);
            float4 b3 = *(const float4*)(bb + 24);
            float bias[16] = {b0.x, b0.y, b0.z, b0.w, b1.x, b1.y, b1.z, b1.w,
                              b2.x, b2.y, b2.z, b2.w, b3.x, b3.y, b3.z, b3.w};
            unsigned int pr[8];
            #pragma unroll
            for (int i = 0; i < 8; ++i) {
                pr[i] = bf16pair(gelu_f(c1[2*i]   + bias[2*i]),
                                 gelu_f(c1[2*i+1] + bias[2*i+1]));
            }
            unsigned int rx0 = __shfl_xor(islo ? pr[2] : pr[0], 32);
            unsigned int rx1 = __shfl_xor(islo ? pr[3] : pr[1], 32);
            unsigned int rx2 = __shfl_xor(islo ? pr[6] : pr[4], 32);
            unsigned int rx3 = __shfl_xor(islo ? pr[7] : pr[5], 32);
            short8 pa0 = mk8(islo ? pr[0] : rx0, islo ? pr[1] : rx1,
                             islo ? rx0 : pr[2], islo ? rx1 : pr[3]);
            short8 pa1 = mk8(islo ? pr[4] : rx2, islo ? pr[5] : rx3,
                             islo ? rx2 : pr[6], islo ? rx3 : pr[7]);

            // GEMM2 partial: window k-groups kg = ch*2 (pa0), ch*2+1 (pa1);
            // B-frags via paired 8B reads (granule XOR c&15, 2-way = free)
            #pragma unroll
            for (int ct = 0; ct < 4; ++ct) {
                int c = ct*32 + l31;
                const char* rb = (const char*)w2c[cur] + c*128;
                int xm = c & 15;
                int ga = ch*8 + lh*2;
                int gb = ch*8 + 4 + lh*2;
                u64 q0 = *(const u64*)(rb + (((ga    ) ^ xm) << 3));
                u64 q1 = *(const u64*)(rb + (((ga + 1) ^ xm) << 3));
                u64 q2 = *(const u64*)(rb + (((gb    ) ^ xm) << 3));
                u64 q3 = *(const u64*)(rb + (((gb + 1) ^ xm) << 3));
                short8 bf0 = mkq(q0, q1);
                short8 bf1 = mkq(q2, q3);
                if (ct == 0) { o0 = MFMA_B(pa0, bf0, o0); o0 = MFMA_B(pa1, bf1, o0); }
                else if (ct == 1) { o1 = MFMA_B(pa0, bf0, o1); o1 = MFMA_B(pa1, bf1, o1); }
                else if (ct == 2) { o2 = MFMA_B(pa0, bf0, o2); o2 = MFMA_B(pa1, bf1, o2); }
                else              { o3 = MFMA_B(pa0, bf0, o3); o3 = MFMA_B(pa1, bf1, o3); }
            }
        }
        __builtin_amdgcn_s_barrier();   // reads done; next stage may overwrite
    }

    // epilogue: gate * exp(out + fc2_b) -> bf16 scatter to outbuf[a]
    float bc0 = fc2_b[(size_t)e*CDIM + l31];
    float bc1 = fc2_b[(size_t)e*CDIM + 32 + l31];
    float bc2 = fc2_b[(size_t)e*CDIM + 64 + l31];
    float bc3 = fc2_b[(size_t)e*CDIM + 96 + l31];
    #pragma unroll
    for (int rr = 0; rr < 16; ++rr) {
        int crow = (rr & 3) + 8*(rr >> 2) + 4*lh;
        int av   = __shfl(a, crow);
        float gv = __shfl(g, crow);
        if (av < 0) continue;
        unsigned short* po = outbuf + (size_t)av*CDIM + l31;
        po[0]  = (unsigned short)bf16_1(gv * __expf(o0[rr] + bc0));
        po[32] = (unsigned short)bf16_1(gv * __expf(o1[rr] + bc1));
        po[64] = (unsigned short)bf16_1(gv * __expf(o2[rr] + bc2));
        po[96] = (unsigned short)bf16_1(gv * __expf(o3[rr] + bc3));
    }
}

// K4: y = log(p0 + p1) from bf16 partials, transpose back to (B,C,H,W)
__global__ __launch_bounds__(256) void combine_kernel(
    const unsigned short* __restrict__ outbuf, float* __restrict__ out)
{
    __shared__ float ys[64][129];
    const int t = threadIdx.x;
    const int n0 = blockIdx.x * 64;
    const int b = n0 >> 14;
    const int hw0 = n0 & (HW - 1);
    #pragma unroll
    for (int i = 0; i < 4; ++i) {
        int idx = t + 256 * i;            // 1024 tasks: token x 16-col group
        int tk = idx >> 4, c8 = (idx & 15) * 8;
        const unsigned short* p = outbuf + (size_t)(n0 + tk) * 256 + c8;
        ushort8v p0 = *(const ushort8v*)p;
        ushort8v p1 = *(const ushort8v*)(p + 128);
        const float EPSL = 2.2204460492503131e-16f;
        #pragma unroll
        for (int j = 0; j < 8; ++j) {
            float v = __uint_as_float((unsigned)p0[j] << 16)
                    + __uint_as_float((unsigned)p1[j] << 16);
            ys[tk][c8 + j] = __logf(v == 0.f ? EPSL : v);
        }
    }
    __syncthreads();
    float* ob = out + (size_t)b * CDIM * HW + hw0;
    #pragma unroll 4
    for (int i = 0; i < 32; ++i) {
        int idx = t + 256 * i;
        int c = idx >> 6;
        int j = idx & 63;
        ob[(size_t)c * HW + j] = ys[j][c];
    }
}

extern "C" void kernel_launch(void* const* d_in, const int* in_sizes, int n_in,
                              void* d_out, int out_size, void* d_ws, size_t ws_size,
                              hipStream_t stream)
{
    const float* x       = (const float*)d_in[0];
    const float* prompt  = (const float*)d_in[1];
    const float* de_cls  = (const float*)d_in[2];
    const float* w_g     = (const float*)d_in[3];
    const float* gboost  = (const float*)d_in[4];
    const float* degra_w = (const float*)d_in[5];
    const float* degra_b = (const float*)d_in[6];
    const float* fc1_w   = (const float*)d_in[7];
    const float* fc1_b   = (const float*)d_in[8];
    const float* fc2_w   = (const float*)d_in[9];
    const float* fc2_b   = (const float*)d_in[10];
    float* out = (float*)d_out;
    char* ws = (char*)d_ws;

    unsigned short* xfb  = (unsigned short*)(ws + OFF_XFB);
    int*   list   = (int*)(ws + OFF_LIST);
    float* gates  = (float*)(ws + OFF_GATES);
    unsigned short* outbuf = (unsigned short*)(ws + OFF_OUTBUF);
    unsigned short* wt1 = (unsigned short*)(ws + OFF_WT1);
    unsigned short* wt2 = (unsigned short*)(ws + OFF_WT2);
    float* bias   = (float*)(ws + OFF_BIAS);
    int*   cnt    = (int*)(ws + OFF_CNT);
    float* wsum   = (float*)(ws + OFF_WSUM);

    prep_kernel<<<1, 64, 0, stream>>>(prompt, de_cls, w_g, gboost, degra_w,
                                      degra_b, bias, cnt, wsum);
    wconv_kernel<<<48, 256, 0, stream>>>(fc1_w, fc2_w, wt1, wt2);
    gate_kernel<<<512, 256, 0, stream>>>(x, w_g, bias, xfb, list, gates, cnt, wsum);
    loss_kernel<<<1, 64, 0, stream>>>(cnt, wsum, out + (size_t)NTOK * CDIM);
    dim3 eg(NEXP, 256);   // 128-token / 4-wave blocks
    expert_kernel<<<eg, 256, 0, stream>>>(xfb, list, cnt, gates, wt1, wt2,
                                          fc1_b, fc2_b, outbuf);
    combine_kernel<<<512, 256, 0, stream>>>(outbuf, out);
}

// Round 14
// 112.778 us; speedup vs baseline: 1.5266x; 1.0519x over previous
//
#include <hip/hip_runtime.h>
#include <math.h>

#define HW    16384
#define NTOK  32768
#define CDIM  128
#define HFDIM 512
#define NEXP  6

typedef __attribute__((ext_vector_type(8))) short short8;
typedef __attribute__((ext_vector_type(8))) unsigned short ushort8v;
typedef __attribute__((ext_vector_type(16))) float f32x16;
typedef unsigned long long u64;

// workspace byte offsets (256-aligned)
#define OFF_XFB    0UL          // N*128 bf16      = 8,388,608
#define OFF_LIST   8388608UL    // E*N int         =   786,432
#define OFF_GATES  9175040UL    // 2N float        =   262,144
#define OFF_OUTBUF 9437184UL    // 2N*128 bf16     = 16,777,216
#define OFF_WT1    42991616UL   // E*4*16384 bf16  =   786,432  [e][g][hf128][k128] swz16
#define OFF_WT2    43778048UL   // E*8*8192 bf16   =   786,432  [e][gp][c128][k64] swz16-8B
#define OFF_BIAS   44564480UL
#define OFF_CNT    44564736UL
#define OFF_WSUM   44564992UL

__device__ __forceinline__ unsigned int bf16_1(float f) {
    unsigned int u = __float_as_uint(f);
    return (u + 0x7FFFu + ((u >> 16) & 1)) >> 16;
}
__device__ __forceinline__ unsigned int bf16pair(float lo, float hi) {
    return bf16_1(lo) | (bf16_1(hi) << 16);
}
// sigmoid-form gelu: x*sigmoid(1.702x); ~5 VALU inst
__device__ __forceinline__ float gelu_f(float v) {
    return __fdividef(v, 1.0f + __expf(-1.702f * v));
}
__device__ __forceinline__ short8 mkq(u64 lo, u64 hi) {
    union { u64 q[2]; short8 s; } x;
    x.q[0] = lo; x.q[1] = hi;
    return x.s;
}

#define GLDS16(src, dst) __builtin_amdgcn_global_load_lds( \
    (const __attribute__((address_space(1))) void*)(src),  \
    (__attribute__((address_space(3))) void*)(dst), 16, 0, 0)

__device__ __forceinline__ f32x16 MFMA_B(short8 a, short8 b, f32x16 c) {
    return __builtin_amdgcn_mfma_f32_32x32x16_bf16(a, b, c, 0, 0, 0);
}

// K0: per-batch gating bias + zero atomics (deterministic per call)
__global__ __launch_bounds__(64) void prep_kernel(
    const float* __restrict__ prompt, const float* __restrict__ de_cls,
    const float* __restrict__ w_g, const float* __restrict__ gate_boost,
    const float* __restrict__ degra_w, const float* __restrict__ degra_b,
    float* __restrict__ bias, int* __restrict__ cnt, float* __restrict__ wsum)
{
    int t = threadIdx.x;
    if (t < 2 * NEXP) {
        int b = t / NEXP, e = t % NEXP;
        float acc = 0.f;
        for (int c = 0; c < CDIM; ++c)
            acc = fmaf(prompt[b*CDIM + c], w_g[(CDIM + c)*NEXP + e], acc);
        float db = 0.f;
        for (int d = 0; d < 6; ++d)
            db = fmaf(de_cls[b*6 + d], degra_w[d*NEXP + e], db);
        bias[b*NEXP + e] = acc + gate_boost[0] * (db + degra_b[e]);
    }
    if (t >= 32 && t < 32 + NEXP) cnt[t - 32] = 0;
    if (t >= 40 && t < 40 + NEXP) wsum[t - 40] = 0.f;
}

// Kw: fp32 weights -> bf16, pre-permuted so LINEAR global_load_lds copies
// yield the desired LDS images.  (r12/r13-verified, unchanged)
// wt1: [e][g 4][hf 128][k=C 128] rows 256B, 16-slot(16B) XOR (hf&15)
// wt2: [e][gp 8][c 128][k=hf 64] rows 128B, 16-granule(8B) XOR (c&15)
__global__ __launch_bounds__(256) void wconv_kernel(
    const float* __restrict__ fc1_w, const float* __restrict__ fc2_w,
    unsigned short* __restrict__ wt1, unsigned short* __restrict__ wt2)
{
    __shared__ unsigned short ls[128][128];   // [k][col] bf16, 32 KB
    const int bid = blockIdx.x;               // e*8 + which*4 + chunk
    const int e = bid >> 3, which = (bid >> 2) & 1, ch = bid & 3;
    const int t = threadIdx.x;
    #pragma unroll 4
    for (int i = 0; i < 16; ++i) {
        int id = t + 256 * i;                 // 4096 float4 tasks
        int k = id >> 5, q = id & 31;
        const float* p = which
            ? (fc2_w + (size_t)e*65536 + (size_t)(ch*128 + k)*128 + q*4)
            : (fc1_w + (size_t)e*65536 + (size_t)k*512 + ch*128 + q*4);
        float4 v = *(const float4*)p;
        u64 pk = (u64)bf16_1(v.x) | ((u64)bf16_1(v.y) << 16)
               | ((u64)bf16_1(v.z) << 32) | ((u64)bf16_1(v.w) << 48);
        *(u64*)&ls[k][q*4] = pk;
    }
    __syncthreads();
    #pragma unroll 2
    for (int i = 0; i < 8; ++i) {
        int id = t + 256 * i;                 // 2048 tasks: (col, kg)
        int col = id & 127, kg = id >> 7;     // kg = k-group of 8 (0..15)
        unsigned short v[8];
        #pragma unroll
        for (int j = 0; j < 8; ++j) v[j] = ls[kg*8 + j][col];
        u64 lo = (u64)v[0] | ((u64)v[1] << 16) | ((u64)v[2] << 32) | ((u64)v[3] << 48);
        u64 hi = (u64)v[4] | ((u64)v[5] << 16) | ((u64)v[6] << 32) | ((u64)v[7] << 48);
        if (which) {
            int h  = kg >> 3;
            int g0 = (kg & 7) * 2;
            unsigned short* d = wt2 + (size_t)e*65536 + (size_t)(ch*2 + h)*8192
                              + (size_t)col*64;
            *(u64*)(d + (((g0    ) ^ (col & 15)) << 2)) = lo;
            *(u64*)(d + (((g0 + 1) ^ (col & 15)) << 2)) = hi;
        } else {
            int4 pk;
            pk.x = (unsigned)(lo & 0xFFFFFFFFu); pk.y = (unsigned)(lo >> 32);
            pk.z = (unsigned)(hi & 0xFFFFFFFFu); pk.w = (unsigned)(hi >> 32);
            *(int4*)(wt1 + (((size_t)(e*4 + ch)) << 14)
                     + (size_t)col*128 + (((kg ^ (col & 15)) & 15) << 3)) = pk;
        }
    }
}

// K1: transpose x -> xfb (token-major bf16), gating, top-2 softmax, lists.
__global__ __launch_bounds__(256) void gate_kernel(
    const float* __restrict__ x, const float* __restrict__ w_g,
    const float* __restrict__ bias, unsigned short* __restrict__ xfb,
    int* __restrict__ list, float* __restrict__ gates,
    int* __restrict__ cnt, float* __restrict__ wsum)
{
    __shared__ float xs[CDIM][65];
    __shared__ float wgs[CDIM][NEXP];
    __shared__ int   cnt_s[NEXP];
    __shared__ float ws_s[NEXP];
    __shared__ int   base_s[NEXP];
    const int t = threadIdx.x;
    const int n0 = blockIdx.x * 64;
    const int b = n0 >> 14;
    const int hw0 = n0 & (HW - 1);

    for (int i = t; i < CDIM * NEXP; i += 256) wgs[i / NEXP][i % NEXP] = w_g[i];
    if (t < NEXP) { cnt_s[t] = 0; ws_s[t] = 0.f; }

    const float* xb = x + (size_t)b * CDIM * HW + hw0;
    #pragma unroll 4
    for (int i = 0; i < 32; ++i) {
        int idx = t + 256 * i;
        int c = idx >> 6, j = idx & 63;
        xs[c][j] = xb[(size_t)c * HW + j];
    }
    __syncthreads();
    unsigned int* xo = (unsigned int*)xfb;
    #pragma unroll 4
    for (int i = 0; i < 16; ++i) {
        int idx = t + 256 * i;
        int tk = idx >> 6, cp = idx & 63;
        xo[(size_t)(n0 + tk) * 64 + cp] = bf16pair(xs[2*cp][tk], xs[2*cp+1][tk]);
    }

    int i0 = 0, i1 = 0, s0 = 0, s1 = 0;
    float g0 = 0.f, g1 = 0.f;
    if (t < 64) {
        float lg[NEXP];
        #pragma unroll
        for (int e = 0; e < NEXP; ++e) lg[e] = bias[b*NEXP + e];
        for (int c = 0; c < CDIM; ++c) {
            float xv = xs[c][t];
            #pragma unroll
            for (int e = 0; e < NEXP; ++e) lg[e] = fmaf(xv, wgs[c][e], lg[e]);
        }
        i0 = 0;
        #pragma unroll
        for (int e = 1; e < NEXP; ++e) if (lg[e] > lg[i0]) i0 = e;
        i1 = (i0 == 0) ? 1 : 0;
        #pragma unroll
        for (int e = 0; e < NEXP; ++e) if (e != i0 && lg[e] > lg[i1]) i1 = e;
        float e1 = expf(lg[i1] - lg[i0]);
        g0 = 1.f / (1.f + e1);
        g1 = e1 * g0;
        s0 = atomicAdd(&cnt_s[i0], 1);
        s1 = atomicAdd(&cnt_s[i1], 1);
        atomicAdd(&ws_s[i0], g0);
        atomicAdd(&ws_s[i1], g1);
    }
    __syncthreads();
    if (t < NEXP) {
        base_s[t] = atomicAdd(&cnt[t], cnt_s[t]);
        atomicAdd(&wsum[t], ws_s[t]);
    }
    __syncthreads();
    if (t < 64) {
        int n = n0 + t;
        list[i0 * NTOK + base_s[i0] + s0] = 2 * n;
        list[i1 * NTOK + base_s[i1] + s1] = 2 * n + 1;
        gates[2 * n]     = g0;
        gates[2 * n + 1] = g1;
    }
}

// K2: balance loss
__global__ void loss_kernel(const int* __restrict__ cnt,
                            const float* __restrict__ wsum,
                            float* __restrict__ out_loss)
{
    if (threadIdx.x == 0 && blockIdx.x == 0) {
        float mw = 0.f, mc = 0.f;
        for (int e = 0; e < NEXP; ++e) { mw += wsum[e]; mc += (float)cnt[e]; }
        mw /= NEXP; mc /= NEXP;
        float vw = 0.f, vc = 0.f;
        for (int e = 0; e < NEXP; ++e) {
            float dw = wsum[e] - mw, dc = (float)cnt[e] - mc;
            vw += dw * dw; vc += dc * dc;
        }
        vw /= (NEXP - 1); vc /= (NEXP - 1);
        out_loss[0] = vw / (mw * mw + 1e-10f) + vc / (mc * mc + 1e-10f);
    }
}

// K3: residency-max MoE MLP. Block = 64 tokens, 4 waves: wave = (token-half,
// role-half). GEMM1: wave computes its 32-hf half of each 64-hf window (no
// duplication); hid -> hsb (b32 packed, 8B-granule XOR(tok&15), 2-way free).
// GEMM2: wave re-splits by c-half, k = window hf. LDS = 16K w1 + 16K w2 +
// 8K hs = 40KB single-buffered -> 4 blocks/CU = 16 waves/CU (4104 waves
// total, r6-level residency) with r13's counted-vmcnt staging: stage-W1(gp+1)
// before GEMM2(gp), stage-W2(gp+1) after it; vmcnt(4) at consume points.
__global__ __launch_bounds__(256, 4) void expert_kernel(
    const unsigned short* __restrict__ xfb, const int* __restrict__ list,
    const int* __restrict__ cnt, const float* __restrict__ gates,
    const unsigned short* __restrict__ wt1, const unsigned short* __restrict__ wt2,
    const float* __restrict__ fc1_b, const float* __restrict__ fc2_b,
    unsigned short* __restrict__ outbuf)
{
    __shared__ unsigned short w1c[8192];   // 16 KB [64 hf][128 k]  swz16 (16B)
    __shared__ unsigned short w2c[8192];   // 16 KB [128 c][64 k]   swz16 (8B)
    __shared__ unsigned short hsb[4096];   //  8 KB [64 tok][64 hf] swz16 (8B)
    const int e = blockIdx.x;
    const int ne = cnt[e];
    const int base = blockIdx.y * 64;
    if (base >= ne) return;
    const int t = threadIdx.x;
    const int w = t >> 6, l = t & 63;
    const int l31 = l & 31, lh = l >> 5;
    const int th = w & 1;          // token half
    const int rh = w >> 1;         // role half (hf-half in GEMM1, c-half in GEMM2)

    int r = base + th*32 + l31;
    int a = (r < ne) ? list[e*NTOK + r] : -1;
    float g = (a >= 0) ? gates[a] : 0.f;
    int tok = (a >= 0) ? (a >> 1) : 0;

    // X B-fragments: lane holds X[k = ks*16 + lh*8 ..+7][its token]
    short8 afr[8];
    {
        const unsigned short* xr = xfb + (size_t)tok*128 + lh*8;
        #pragma unroll
        for (int ks = 0; ks < 8; ++ks)
            afr[ks] = *(const short8*)(xr + ks*16);
    }

    f32x16 zz;
    #pragma unroll
    for (int i = 0; i < 16; ++i) zz[i] = 0.0f;
    f32x16 o0 = zz, o1 = zz;

    // each wave stages a 4KB quarter of a 16KB window (4 x 1KB loads)
    auto STG1 = [&](int gp) {
        const unsigned short* s1 = wt1 + (((size_t)(e*4 + (gp >> 1))) << 14)
                                 + (gp & 1)*8192 + w*2048 + l*8;
        #pragma unroll
        for (int i = 0; i < 4; ++i)
            GLDS16(s1 + i*512, &w1c[w*2048 + i*512]);
    };
    auto STG2 = [&](int gp) {
        const unsigned short* s2 = wt2 + (size_t)e*65536 + (size_t)gp*8192
                                 + w*2048 + l*8;
        #pragma unroll
        for (int i = 0; i < 4; ++i)
            GLDS16(s2 + i*512, &w2c[w*2048 + i*512]);
    };

    STG1(0);
    STG2(0);

    const int tk = th*32 + l31;
    const int xm = tk & 15;

    for (int gp = 0; gp < 8; ++gp) {          // 64-hf windows
        // own W1(gp) retired (oldest 4 of 8 in flight); all waves synced
        asm volatile("s_waitcnt vmcnt(4)" ::: "memory");
        __builtin_amdgcn_s_barrier();

        // A: GEMM1 rows rh*32 + l31 of the window, k = C = 128
        f32x16 c1 = zz;
        {
            int arow = rh*32 + l31;
            #pragma unroll
            for (int ks = 0; ks < 8; ++ks) {
                int kk = ks*2 + lh;
                short8 wf = *(const short8*)((const char*)w1c + arow*256
                             + (((kk ^ (arow & 15)) & 15) << 4));
                c1 = MFMA_B(wf, afr[ks], c1);
            }
        }
        // bias + gelu + pair-pack -> 8 b32 writes into swizzled hsb
        {
            const float* bb = fc1_b + (size_t)e*HFDIM + gp*64 + rh*32 + 4*lh;
            float4 b0 = *(const float4*)(bb);
            float4 b1 = *(const float4*)(bb + 8);
            float4 b2 = *(const float4*)(bb + 16);
            float4 b3 = *(const float4*)(bb + 24);
            float bias[16] = {b0.x, b0.y, b0.z, b0.w, b1.x, b1.y, b1.z, b1.w,
                              b2.x, b2.y, b2.z, b2.w, b3.x, b3.y, b3.z, b3.w};
            #pragma unroll
            for (int i = 0; i < 8; ++i) {
                unsigned int pv = bf16pair(gelu_f(c1[2*i]   + bias[2*i]),
                                           gelu_f(c1[2*i+1] + bias[2*i+1]));
                // window-local hf of this pair's first element
                int hf0 = rh*32 + 4*lh + (i & 1)*2 + (i >> 1)*8;
                int gg  = hf0 >> 2;                      // 8B granule
                *(unsigned int*)((char*)hsb + tk*128 + ((gg ^ xm) << 3)
                                 + ((hf0 & 3) << 1)) = pv;
            }
        }
        asm volatile("s_waitcnt lgkmcnt(0)" ::: "memory");
        __builtin_amdgcn_sched_barrier(0);
        __builtin_amdgcn_s_barrier();          // hsb visible; w1 reads done

        // B: issue W1(gp+1) (covered by GEMM2), retire W2(gp), GEMM2
        if (gp < 7) {
            STG1(gp + 1);
            asm volatile("s_waitcnt vmcnt(4)" ::: "memory");
        } else {
            asm volatile("s_waitcnt vmcnt(0)" ::: "memory");
        }
        __builtin_amdgcn_s_barrier();

        #pragma unroll
        for (int kg = 0; kg < 4; ++kg) {       // k = kg*16 + lh*8 (window-local)
            int ga = kg*4 + lh*2;
            const char* ra = (const char*)hsb + tk*128;
            u64 a0 = *(const u64*)(ra + (((ga    ) ^ xm) << 3));
            u64 a1 = *(const u64*)(ra + (((ga + 1) ^ xm) << 3));
            short8 af2 = mkq(a0, a1);
            #pragma unroll
            for (int ct = 0; ct < 2; ++ct) {
                int c = rh*64 + ct*32 + l31;
                const char* rb = (const char*)w2c + c*128;
                int xb = c & 15;
                u64 q0 = *(const u64*)(rb + (((ga    ) ^ xb) << 3));
                u64 q1 = *(const u64*)(rb + (((ga + 1) ^ xb) << 3));
                short8 bf = mkq(q0, q1);
                if (ct == 0) o0 = MFMA_B(af2, bf, o0);
                else         o1 = MFMA_B(af2, bf, o1);
            }
        }
        __builtin_amdgcn_s_barrier();          // w2/hsb reads done
        if (gp < 7) STG2(gp + 1);
    }

    // epilogue: gate * exp(out + fc2_b) -> bf16 scatter (wave's c-half)
    float bc0 = fc2_b[(size_t)e*CDIM + rh*64 + l31];
    float bc1 = fc2_b[(size_t)e*CDIM + rh*64 + 32 + l31];
    #pragma unroll
    for (int rr = 0; rr < 16; ++rr) {
        int crow = (rr & 3) + 8*(rr >> 2) + 4*lh;
        int av   = __shfl(a, crow);            // token at lane crow (same half)
        float gv = __shfl(g, crow);
        if (av < 0) continue;
        unsigned short* po = outbuf + (size_t)av*CDIM + rh*64 + l31;
        po[0]  = (unsigned short)bf16_1(gv * __expf(o0[rr] + bc0));
        po[32] = (unsigned short)bf16_1(gv * __expf(o1[rr] + bc1));
    }
}

// K4: y = log(p0 + p1) from bf16 partials, transpose back to (B,C,H,W)
__global__ __launch_bounds__(256) void combine_kernel(
    const unsigned short* __restrict__ outbuf, float* __restrict__ out)
{
    __shared__ float ys[64][129];
    const int t = threadIdx.x;
    const int n0 = blockIdx.x * 64;
    const int b = n0 >> 14;
    const int hw0 = n0 & (HW - 1);
    #pragma unroll
    for (int i = 0; i < 4; ++i) {
        int idx = t + 256 * i;            // 1024 tasks: token x 16-col group
        int tk = idx >> 4, c8 = (idx & 15) * 8;
        const unsigned short* p = outbuf + (size_t)(n0 + tk) * 256 + c8;
        ushort8v p0 = *(const ushort8v*)p;
        ushort8v p1 = *(const ushort8v*)(p + 128);
        const float EPSL = 2.2204460492503131e-16f;
        #pragma unroll
        for (int j = 0; j < 8; ++j) {
            float v = __uint_as_float((unsigned)p0[j] << 16)
                    + __uint_as_float((unsigned)p1[j] << 16);
            ys[tk][c8 + j] = __logf(v == 0.f ? EPSL : v);
        }
    }
    __syncthreads();
    float* ob = out + (size_t)b * CDIM * HW + hw0;
    #pragma unroll 4
    for (int i = 0; i < 32; ++i) {
        int idx = t + 256 * i;
        int c = idx >> 6;
        int j = idx & 63;
        ob[(size_t)c * HW + j] = ys[j][c];
    }
}

extern "C" void kernel_launch(void* const* d_in, const int* in_sizes, int n_in,
                              void* d_out, int out_size, void* d_ws, size_t ws_size,
                              hipStream_t stream)
{
    const float* x       = (const float*)d_in[0];
    const float* prompt  = (const float*)d_in[1];
    const float* de_cls  = (const float*)d_in[2];
    const float* w_g     = (const float*)d_in[3];
    const float* gboost  = (const float*)d_in[4];
    const float* degra_w = (const float*)d_in[5];
    const float* degra_b = (const float*)d_in[6];
    const float* fc1_w   = (const float*)d_in[7];
    const float* fc1_b   = (const float*)d_in[8];
    const float* fc2_w   = (const float*)d_in[9];
    const float* fc2_b   = (const float*)d_in[10];
    float* out = (float*)d_out;
    char* ws = (char*)d_ws;

    unsigned short* xfb  = (unsigned short*)(ws + OFF_XFB);
    int*   list   = (int*)(ws + OFF_LIST);
    float* gates  = (float*)(ws + OFF_GATES);
    unsigned short* outbuf = (unsigned short*)(ws + OFF_OUTBUF);
    unsigned short* wt1 = (unsigned short*)(ws + OFF_WT1);
    unsigned short* wt2 = (unsigned short*)(ws + OFF_WT2);
    float* bias   = (float*)(ws + OFF_BIAS);
    int*   cnt    = (int*)(ws + OFF_CNT);
    float* wsum   = (float*)(ws + OFF_WSUM);

    prep_kernel<<<1, 64, 0, stream>>>(prompt, de_cls, w_g, gboost, degra_w,
                                      degra_b, bias, cnt, wsum);
    wconv_kernel<<<48, 256, 0, stream>>>(fc1_w, fc2_w, wt1, wt2);
    gate_kernel<<<512, 256, 0, stream>>>(x, w_g, bias, xfb, list, gates, cnt, wsum);
    loss_kernel<<<1, 64, 0, stream>>>(cnt, wsum, out + (size_t)NTOK * CDIM);
    dim3 eg(NEXP, 512);   // 64-token / 4-wave blocks (4104 waves, 16/CU)
    expert_kernel<<<eg, 256, 0, stream>>>(xfb, list, cnt, gates, wt1, wt2,
                                          fc1_b, fc2_b, outbuf);
    combine_kernel<<<512, 256, 0, stream>>>(outbuf, out);
}